// Round 5
// baseline (821.710 us; speedup 1.0000x reference)
//
#include <hip/hip_runtime.h>
#include <hip/hip_bf16.h>

typedef __bf16 bf16x8 __attribute__((ext_vector_type(8)));
typedef __bf16 bf16x4 __attribute__((ext_vector_type(4)));
typedef __bf16 bf16x2 __attribute__((ext_vector_type(2)));
typedef float f32x4 __attribute__((ext_vector_type(4)));
typedef unsigned u32x4 __attribute__((ext_vector_type(4)));

// ---------------- dtype-robust load helpers ----------------
__device__ __forceinline__ float getf(const void* p, size_t i, int isf32){
  return isf32 ? ((const float*)p)[i]
               : __bfloat162float(((const __hip_bfloat16*)p)[i]);
}
__device__ __forceinline__ int getedge(const void* p, long long idx, int is64, int n){
  long long v = is64 ? ((const long long*)p)[idx] : (long long)((const int*)p)[idx];
  v = v < 0 ? 0 : (v >= n ? (long long)(n - 1) : v);
  return (int)v;
}

__device__ __forceinline__ float bfly_sum(float v){
#pragma unroll
  for (int m = 32; m > 0; m >>= 1) v += __shfl_xor(v, m, 64);
  return v;
}

__device__ __forceinline__ float bf_lo(unsigned u){ return __uint_as_float(u << 16); }
__device__ __forceinline__ float bf_hi(unsigned u){ return __uint_as_float(u & 0xffff0000u); }

// ---------------- runtime dtype detection ----------------
__global__ __launch_bounds__(256) void detect_kernel(const void* x, const void* ei,
                                                     int* flags){
  __shared__ int cnt_sane, cnt_odd;
  int t = threadIdx.x;
  if (t == 0){ cnt_sane = 0; cnt_odd = 0; }
  __syncthreads();
  int sane = 0;
  for (int i = t; i < 4096; i += 256){
    float v = __bfloat162float(((const __hip_bfloat16*)x)[i]);
    if (fabsf(v) < 16.f) sane++;
  }
  atomicAdd(&cnt_sane, sane);
  int odd = 0;
  for (int i = t; i < 512; i += 256){
    if (((const int*)ei)[2 * i + 1] != 0) odd++;
  }
  atomicAdd(&cnt_odd, odd);
  __syncthreads();
  if (t == 0){
    flags[0] = (cnt_sane < 3900) ? 1 : 0;  // 1 => float inputs are fp32
    flags[1] = (cnt_odd == 0) ? 1 : 0;     // 1 => edge_index is int64
  }
}

// ---------------- graph bucketing ----------------
__global__ __launch_bounds__(256) void count_kernel(const void* __restrict__ ei, long long E,
                                                    int n, const int* __restrict__ flags,
                                                    int* __restrict__ cnt){
  int i = blockIdx.x * blockDim.x + threadIdx.x;
  if (i < E){
    int d = getedge(ei, E + i, flags[1], n);
    atomicAdd(&cnt[d], 1);
  }
}

// 4x-vectorized single-block scan
__global__ __launch_bounds__(1024) void scan_kernel(const int* __restrict__ cnt, int* __restrict__ off,
                                                    int* __restrict__ pos, int n){
  __shared__ int wsum[16];
  __shared__ int carry_s;
  int tid = threadIdx.x, lane = tid & 63, wv = tid >> 6;
  if (tid == 0) carry_s = 0;
  __syncthreads();
  for (int base = 0; base < n; base += 4096){
    int i0 = base + tid * 4;
    int v0 = 0, v1 = 0, v2 = 0, v3 = 0;
    if (i0 + 3 < n){
      int4 q = *(const int4*)(cnt + i0);
      v0 = q.x; v1 = q.y; v2 = q.z; v3 = q.w;
    } else {
      if (i0 < n)     v0 = cnt[i0];
      if (i0 + 1 < n) v1 = cnt[i0 + 1];
      if (i0 + 2 < n) v2 = cnt[i0 + 2];
      if (i0 + 3 < n) v3 = cnt[i0 + 3];
    }
    int s4 = v0 + v1 + v2 + v3;
    int s = s4;
#pragma unroll
    for (int o = 1; o < 64; o <<= 1){ int t = __shfl_up(s, o, 64); if (lane >= o) s += t; }
    if (lane == 63) wsum[wv] = s;
    __syncthreads();
    int wo = 0;
    for (int w = 0; w < wv; w++) wo += wsum[w];
    int carry = carry_s;
    int e0 = carry + wo + s - s4;
    if (i0 + 3 < n){
      int4 o4; o4.x = e0; o4.y = e0 + v0; o4.z = e0 + v0 + v1; o4.w = e0 + v0 + v1 + v2;
      *(int4*)(off + i0) = o4;
      *(int4*)(pos + i0) = o4;
    } else {
      if (i0 < n)     { off[i0] = e0;               pos[i0] = e0; }
      if (i0 + 1 < n) { off[i0+1] = e0+v0;          pos[i0+1] = e0+v0; }
      if (i0 + 2 < n) { off[i0+2] = e0+v0+v1;       pos[i0+2] = e0+v0+v1; }
      if (i0 + 3 < n) { off[i0+3] = e0+v0+v1+v2;    pos[i0+3] = e0+v0+v1+v2; }
    }
    __syncthreads();
    if (tid == 0){
      int tot = 0;
      for (int w = 0; w < 16; w++) tot += wsum[w];
      carry_s = carry + tot;
    }
    __syncthreads();
  }
  if (tid == 0) off[n] = carry_s;
}

__global__ __launch_bounds__(256) void fill_kernel(const void* __restrict__ ei, long long E,
                                                   int n, const int* __restrict__ flags,
                                                   int* __restrict__ pos, int* __restrict__ bsrc){
  int i = blockIdx.x * blockDim.x + threadIdx.x;
  if (i < E){
    int d = getedge(ei, E + i, flags[1], n);
    int s = getedge(ei, i, flags[1], n);
    int p = atomicAdd(&pos[d], 1);
    bsrc[p] = s;
  }
}

// ---------------- degree-descending node order (counting sort, 256 bins) ----------------
__global__ __launch_bounds__(256) void deghist_kernel(const int* __restrict__ cnt, int n,
                                                      int* __restrict__ hist){
  int i = blockIdx.x * 256 + threadIdx.x;
  if (i < n){ int b = min(cnt[i], 255); atomicAdd(&hist[b], 1); }
}

__global__ __launch_bounds__(256) void degscan_kernel(const int* __restrict__ hist,
                                                      int* __restrict__ binpos){
  __shared__ int h[256];
  int t = threadIdx.x;
  h[t] = hist[t];
  __syncthreads();
  if (t == 0){
    int acc = 0;
    for (int b = 255; b >= 0; b--){ int c = h[b]; h[b] = acc; acc += c; }
  }
  __syncthreads();
  binpos[t] = h[t];
}

__global__ __launch_bounds__(256) void degscatter_kernel(const int* __restrict__ cnt, int n,
                                                         int* __restrict__ binpos,
                                                         int* __restrict__ order){
  int i = blockIdx.x * 256 + threadIdx.x;
  if (i < n){
    int b = min(cnt[i], 255);
    int p = atomicAdd(&binpos[b], 1);
    order[p] = i;
  }
}

// ---------------- fused weight pre-transpose: Bt[N][K] (bf16) = W[K][N] ----------------
__global__ __launch_bounds__(256) void transpose_all_kernel(
    const void* __restrict__ Wp, const void* __restrict__ W0,
    const void* __restrict__ W1, const void* __restrict__ Wo,
    const int* __restrict__ flags,
    __hip_bfloat16* __restrict__ btp, __hip_bfloat16* __restrict__ bt0,
    __hip_bfloat16* __restrict__ bt1, __hip_bfloat16* __restrict__ bto)
{
  int f0 = flags[0];
  int o = blockIdx.x * 256 + threadIdx.x;
  const void* W; __hip_bfloat16* B; int K, N, loc;
  if (o < 65536)       { W = Wp; B = btp; K = 256; N = 256; loc = o; }
  else if (o < 131072) { W = W0; B = bt0; K = 256; N = 256; loc = o - 65536; }
  else if (o < 163840) { W = W1; B = bt1; K = 256; N = 128; loc = o - 131072; }
  else if (o < 180224) { W = Wo; B = bto; K = 128; N = 128; loc = o - 163840; }
  else return;
  int nn = loc / K, kk = loc - nn * K;
  B[loc] = __float2bfloat16(getf(W, (size_t)kk * N + nn, f0));
}

// ---------------- LDS-free direct-fragment MFMA GEMM ----------------
__device__ __forceinline__ bf16x8 pk8(f32x4 u, f32x4 w){
  bf16x8 r;
  r[0] = (__bf16)u.x; r[1] = (__bf16)u.y; r[2] = (__bf16)u.z; r[3] = (__bf16)u.w;
  r[4] = (__bf16)w.x; r[5] = (__bf16)w.y; r[6] = (__bf16)w.z; r[7] = (__bf16)w.w;
  return r;
}

template<int AMODE, bool OUTF, bool OUTB, bool RELU, bool BIAS, bool NORM, int ALMODE>
__global__ __launch_bounds__(256) void gemm_direct_kernel(
    const void* __restrict__ A, const __hip_bfloat16* __restrict__ Bt,
    const void* __restrict__ bias, const void* __restrict__ a_s, const void* __restrict__ a_d,
    const int* __restrict__ flags,
    float* __restrict__ Cf, __hip_bfloat16* __restrict__ Cb,
    float* __restrict__ als, float* __restrict__ ald,
    int M, int N, int K)
{
  const int f0 = flags[0];
  const bool af32 = (AMODE == 1) && (f0 != 0);
  int t = threadIdx.x;
  int wave = t >> 6, lane = t & 63;
  int q = lane >> 4, mi = lane & 15;
  int bm = blockIdx.x * 128 + wave * 32;
  int bn = blockIdx.y * 128;

  int r0 = min(bm + mi, M - 1);
  int r1 = min(bm + 16 + mi, M - 1);

  f32x4 acc[2][8] = {};

  if (af32){
    const float* Af = (const float*)A;
    const float* p0 = Af + (size_t)r0 * K + q * 8;
    const float* p1 = Af + (size_t)r1 * K + q * 8;
#pragma unroll 2
    for (int k0 = 0; k0 < K; k0 += 32){
      f32x4 u0 = *(const f32x4*)(p0 + k0);
      f32x4 w0 = *(const f32x4*)(p0 + k0 + 4);
      f32x4 u1 = *(const f32x4*)(p1 + k0);
      f32x4 w1 = *(const f32x4*)(p1 + k0 + 4);
      bf16x8 a0 = pk8(u0, w0);
      bf16x8 a1 = pk8(u1, w1);
#pragma unroll
      for (int nt = 0; nt < 8; nt++){
        bf16x8 b = *(const bf16x8*)(Bt + (size_t)(bn + nt * 16 + mi) * K + k0 + q * 8);
        acc[0][nt] = __builtin_amdgcn_mfma_f32_16x16x32_bf16(a0, b, acc[0][nt], 0, 0, 0);
        acc[1][nt] = __builtin_amdgcn_mfma_f32_16x16x32_bf16(a1, b, acc[1][nt], 0, 0, 0);
      }
    }
  } else {
    const __hip_bfloat16* Ab = (const __hip_bfloat16*)A;
    const __hip_bfloat16* p0 = Ab + (size_t)r0 * K + q * 8;
    const __hip_bfloat16* p1 = Ab + (size_t)r1 * K + q * 8;
#pragma unroll 2
    for (int k0 = 0; k0 < K; k0 += 32){
      bf16x8 a0 = *(const bf16x8*)(p0 + k0);
      bf16x8 a1 = *(const bf16x8*)(p1 + k0);
#pragma unroll
      for (int nt = 0; nt < 8; nt++){
        bf16x8 b = *(const bf16x8*)(Bt + (size_t)(bn + nt * 16 + mi) * K + k0 + q * 8);
        acc[0][nt] = __builtin_amdgcn_mfma_f32_16x16x32_bf16(a0, b, acc[0][nt], 0, 0, 0);
        acc[1][nt] = __builtin_amdgcn_mfma_f32_16x16x32_bf16(a1, b, acc[1][nt], 0, 0, 0);
      }
    }
  }

  float bv[8], asv[8], adv[8];
  if (BIAS){
#pragma unroll
    for (int nt = 0; nt < 8; nt++) bv[nt] = getf(bias, bn + nt * 16 + mi, f0);
  }
  if (ALMODE != 0){
#pragma unroll
    for (int nt = 0; nt < 8; nt++){
      asv[nt] = getf(a_s, bn + nt * 16 + mi, f0);
      adv[nt] = getf(a_d, bn + nt * 16 + mi, f0);
    }
  }
#pragma unroll
  for (int mt = 0; mt < 2; mt++){
#pragma unroll
    for (int r = 0; r < 4; r++){
      int row = bm + mt * 16 + q * 4 + r;
      float vv[8];
#pragma unroll
      for (int nt = 0; nt < 8; nt++){
        float v = acc[mt][nt][r];
        if (BIAS) v += bv[nt];
        if (RELU) v = fmaxf(v, 0.f);
        vv[nt] = v;
      }
      if (NORM){
        float ss = 0.f;
#pragma unroll
        for (int nt = 0; nt < 8; nt++) ss += vv[nt] * vv[nt];
        ss += __shfl_xor(ss, 1, 64);
        ss += __shfl_xor(ss, 2, 64);
        ss += __shfl_xor(ss, 4, 64);
        ss += __shfl_xor(ss, 8, 64);
        float inv = 1.f / fmaxf(sqrtf(ss), 1e-12f);
#pragma unroll
        for (int nt = 0; nt < 8; nt++) vv[nt] *= inv;
      }
      if (ALMODE == 1){
        float ps0 = 0.f, pd0 = 0.f, ps1 = 0.f, pd1 = 0.f;
#pragma unroll
        for (int nt = 0; nt < 4; nt++){ ps0 += vv[nt] * asv[nt]; pd0 += vv[nt] * adv[nt]; }
#pragma unroll
        for (int nt = 4; nt < 8; nt++){ ps1 += vv[nt] * asv[nt]; pd1 += vv[nt] * adv[nt]; }
#pragma unroll
        for (int m = 1; m < 16; m <<= 1){
          ps0 += __shfl_xor(ps0, m, 64); pd0 += __shfl_xor(pd0, m, 64);
          ps1 += __shfl_xor(ps1, m, 64); pd1 += __shfl_xor(pd1, m, 64);
        }
        if ((lane & 15) == 0 && row < M){
          int h0 = blockIdx.y * 2;
          als[(size_t)row * 4 + h0]     = ps0; ald[(size_t)row * 4 + h0]     = pd0;
          als[(size_t)row * 4 + h0 + 1] = ps1; ald[(size_t)row * 4 + h0 + 1] = pd1;
        }
      } else if (ALMODE == 2){
        float ps = 0.f, pd = 0.f;
#pragma unroll
        for (int nt = 0; nt < 8; nt++){ ps += vv[nt] * asv[nt]; pd += vv[nt] * adv[nt]; }
#pragma unroll
        for (int m = 1; m < 16; m <<= 1){
          ps += __shfl_xor(ps, m, 64); pd += __shfl_xor(pd, m, 64);
        }
        if ((lane & 15) == 0 && row < M){ als[row] = ps; ald[row] = pd; }
      }
      if (row < M){
#pragma unroll
        for (int nt = 0; nt < 8; nt++){
          int col = bn + nt * 16 + mi;
          size_t idx = (size_t)row * N + col;
          if (OUTF) Cf[idx] = vv[nt];
          if (OUTB) Cb[idx] = __float2bfloat16(vv[nt]);
        }
      }
    }
  }
}

#define UFMA8(U, W) do { \
  m0 += (W) * bf_lo((U).x); m1 += (W) * bf_hi((U).x); \
  m2 += (W) * bf_lo((U).y); m3 += (W) * bf_hi((U).y); \
  m4 += (W) * bf_lo((U).z); m5 += (W) * bf_hi((U).z); \
  m6 += (W) * bf_lo((U).w); m7 += (W) * bf_hi((U).w); \
} while (0)

#define UFMA4(U, W) do { \
  m0 += (W) * bf_lo((U).x); m1 += (W) * bf_hi((U).x); \
  m2 += (W) * bf_lo((U).y); m3 += (W) * bf_hi((U).y); \
} while (0)

// ---------------- gather0: wave-per-node, half-wave-per-edge, H=4, C=64 ----------------
// lanes 0-31 process even edge slots, lanes 32-63 odd slots; each sub-lane owns
// 8 channels (uint4 = 16B load). Denominator/macc fold with one shfl_xor(32).
// Node order = degree-descending (order[]). Numerics per node unchanged.
__global__ __launch_bounds__(256) void gather0_kernel(
    const __hip_bfloat16* __restrict__ xw, const float* __restrict__ als, const float* __restrict__ ald,
    const int* __restrict__ bsrc, const int* __restrict__ off, const int* __restrict__ order,
    const void* __restrict__ bias, const void* __restrict__ gamma,
    const void* __restrict__ beta, const int* __restrict__ flags,
    __hip_bfloat16* __restrict__ hbuf, int n)
{
  int f0 = flags[0];
  int t = threadIdx.x, wv = t >> 6, lane = t & 63;
  int idx = blockIdx.x * 4 + wv;
  if (idx >= n) return;
  int i = order[idx];
  int es = lane >> 5;          // 0/1: which edge of a pair
  int sl = lane & 31;
  int ch = sl * 8;             // 8 channels per sub-lane
  int head = sl >> 3;          // 0..3
  int e0 = off[i], jend = off[i + 1];

  float m0=0.f,m1=0.f,m2=0.f,m3=0.f,m4=0.f,m5=0.f,m6=0.f,m7=0.f;
  float aldi = ald[(size_t)i * 4 + head];

  float se = als[(size_t)i * 4 + head] + aldi;
  se = (se > 0.f) ? se : 0.2f * se;
  float eself = __expf(se);
  float wacc = 0.f;
  if (es == 0){
    uint4 u = *(const uint4*)(xw + (size_t)i * 256 + ch);
    UFMA8(u, eself);
    wacc = eself;
  }

  // 8 edges per iteration (4 per half-wave), clamped pipeline
  for (int j = e0 + es; j < jend; j += 8){
    int j1 = j + 2, j2 = j + 4, j3 = j + 6;
    int c1 = min(j1, jend - 1), c2 = min(j2, jend - 1), c3 = min(j3, jend - 1);
    int s0 = bsrc[j], s1 = bsrc[c1], s2 = bsrc[c2], s3 = bsrc[c3];
    float l0 = als[(size_t)s0 * 4 + head] + aldi;
    float l1 = als[(size_t)s1 * 4 + head] + aldi;
    float l2 = als[(size_t)s2 * 4 + head] + aldi;
    float l3 = als[(size_t)s3 * 4 + head] + aldi;
    l0 = (l0 > 0.f) ? l0 : 0.2f * l0;
    l1 = (l1 > 0.f) ? l1 : 0.2f * l1;
    l2 = (l2 > 0.f) ? l2 : 0.2f * l2;
    l3 = (l3 > 0.f) ? l3 : 0.2f * l3;
    float w0 = __expf(l0);
    float w1 = (j1 < jend) ? __expf(l1) : 0.f;
    float w2 = (j2 < jend) ? __expf(l2) : 0.f;
    float w3 = (j3 < jend) ? __expf(l3) : 0.f;
    uint4 U0 = *(const uint4*)(xw + (size_t)s0 * 256 + ch);
    uint4 U1 = *(const uint4*)(xw + (size_t)s1 * 256 + ch);
    uint4 U2 = *(const uint4*)(xw + (size_t)s2 * 256 + ch);
    uint4 U3 = *(const uint4*)(xw + (size_t)s3 * 256 + ch);
    wacc += w0 + w1 + w2 + w3;
    UFMA8(U0, w0); UFMA8(U1, w1); UFMA8(U2, w2); UFMA8(U3, w3);
  }

  // fold edge halves (lane^32 holds same channels, other edges)
  m0 += __shfl_xor(m0, 32, 64); m1 += __shfl_xor(m1, 32, 64);
  m2 += __shfl_xor(m2, 32, 64); m3 += __shfl_xor(m3, 32, 64);
  m4 += __shfl_xor(m4, 32, 64); m5 += __shfl_xor(m5, 32, 64);
  m6 += __shfl_xor(m6, 32, 64); m7 += __shfl_xor(m7, 32, 64);
  wacc += __shfl_xor(wacc, 32, 64);

  float rl = 1.f / wacc;
  float v0 = m0 * rl + getf(bias, ch + 0, f0);
  float v1 = m1 * rl + getf(bias, ch + 1, f0);
  float v2 = m2 * rl + getf(bias, ch + 2, f0);
  float v3 = m3 * rl + getf(bias, ch + 3, f0);
  float v4 = m4 * rl + getf(bias, ch + 4, f0);
  float v5 = m5 * rl + getf(bias, ch + 5, f0);
  float v6 = m6 * rl + getf(bias, ch + 6, f0);
  float v7 = m7 * rl + getf(bias, ch + 7, f0);

  // LN over 256 ch; both halves duplicate -> butterfly total is 2x
  float mu = bfly_sum(v0+v1+v2+v3+v4+v5+v6+v7) * (1.f / 512.f);
  float d0=v0-mu,d1=v1-mu,d2=v2-mu,d3=v3-mu,d4=v4-mu,d5=v5-mu,d6=v6-mu,d7=v7-mu;
  float var = bfly_sum(d0*d0+d1*d1+d2*d2+d3*d3+d4*d4+d5*d5+d6*d6+d7*d7) * (1.f / 512.f);
  float rs = rsqrtf(var + 1e-5f);

  if (es == 0){
    u32x4 rbu = __builtin_nontemporal_load((const u32x4*)(hbuf + (size_t)i * 256 + ch));
    bf16x8 rb = __builtin_bit_cast(bf16x8, rbu);
    bf16x8 o;
    float y;
    y = d0 * rs * getf(gamma, ch+0, f0) + getf(beta, ch+0, f0) + (float)rb[0]; o[0] = (__bf16)fmaxf(y, 0.f);
    y = d1 * rs * getf(gamma, ch+1, f0) + getf(beta, ch+1, f0) + (float)rb[1]; o[1] = (__bf16)fmaxf(y, 0.f);
    y = d2 * rs * getf(gamma, ch+2, f0) + getf(beta, ch+2, f0) + (float)rb[2]; o[2] = (__bf16)fmaxf(y, 0.f);
    y = d3 * rs * getf(gamma, ch+3, f0) + getf(beta, ch+3, f0) + (float)rb[3]; o[3] = (__bf16)fmaxf(y, 0.f);
    y = d4 * rs * getf(gamma, ch+4, f0) + getf(beta, ch+4, f0) + (float)rb[4]; o[4] = (__bf16)fmaxf(y, 0.f);
    y = d5 * rs * getf(gamma, ch+5, f0) + getf(beta, ch+5, f0) + (float)rb[5]; o[5] = (__bf16)fmaxf(y, 0.f);
    y = d6 * rs * getf(gamma, ch+6, f0) + getf(beta, ch+6, f0) + (float)rb[6]; o[6] = (__bf16)fmaxf(y, 0.f);
    y = d7 * rs * getf(gamma, ch+7, f0) + getf(beta, ch+7, f0) + (float)rb[7]; o[7] = (__bf16)fmaxf(y, 0.f);
    *(bf16x8*)(hbuf + (size_t)i * 256 + ch) = o;
  }
}

// ---------------- gather1: wave-per-node, half-wave-per-edge, H=1, C=128 ----------------
__global__ __launch_bounds__(256) void gather1_kernel(
    const __hip_bfloat16* __restrict__ xw, const float* __restrict__ als, const float* __restrict__ ald,
    const int* __restrict__ bsrc, const int* __restrict__ off, const int* __restrict__ order,
    const void* __restrict__ bias, const void* __restrict__ gamma,
    const void* __restrict__ beta, const int* __restrict__ flags,
    __hip_bfloat16* __restrict__ outb, int n)
{
  int f0 = flags[0];
  int t = threadIdx.x, wv = t >> 6, lane = t & 63;
  int idx = blockIdx.x * 4 + wv;
  if (idx >= n) return;
  int i = order[idx];
  int es = lane >> 5;
  int sl = lane & 31;
  int ch = sl * 4;             // 4 channels per sub-lane
  int e0 = off[i], jend = off[i + 1];

  float m0=0.f,m1=0.f,m2=0.f,m3=0.f;
  float aldi = ald[i];
  float se = als[i] + aldi;
  se = (se > 0.f) ? se : 0.2f * se;
  float eself = __expf(se);
  float wacc = 0.f;
  if (es == 0){
    uint2 u = *(const uint2*)(xw + (size_t)i * 128 + ch);
    UFMA4(u, eself);
    wacc = eself;
  }

  for (int j = e0 + es; j < jend; j += 8){
    int j1 = j + 2, j2 = j + 4, j3 = j + 6;
    int c1 = min(j1, jend - 1), c2 = min(j2, jend - 1), c3 = min(j3, jend - 1);
    int s0 = bsrc[j], s1 = bsrc[c1], s2 = bsrc[c2], s3 = bsrc[c3];
    float l0 = als[s0] + aldi, l1 = als[s1] + aldi, l2 = als[s2] + aldi, l3 = als[s3] + aldi;
    l0 = (l0 > 0.f) ? l0 : 0.2f * l0;
    l1 = (l1 > 0.f) ? l1 : 0.2f * l1;
    l2 = (l2 > 0.f) ? l2 : 0.2f * l2;
    l3 = (l3 > 0.f) ? l3 : 0.2f * l3;
    float w0 = __expf(l0);
    float w1 = (j1 < jend) ? __expf(l1) : 0.f;
    float w2 = (j2 < jend) ? __expf(l2) : 0.f;
    float w3 = (j3 < jend) ? __expf(l3) : 0.f;
    uint2 U0 = *(const uint2*)(xw + (size_t)s0 * 128 + ch);
    uint2 U1 = *(const uint2*)(xw + (size_t)s1 * 128 + ch);
    uint2 U2 = *(const uint2*)(xw + (size_t)s2 * 128 + ch);
    uint2 U3 = *(const uint2*)(xw + (size_t)s3 * 128 + ch);
    wacc += w0 + w1 + w2 + w3;
    UFMA4(U0, w0); UFMA4(U1, w1); UFMA4(U2, w2); UFMA4(U3, w3);
  }

  m0 += __shfl_xor(m0, 32, 64); m1 += __shfl_xor(m1, 32, 64);
  m2 += __shfl_xor(m2, 32, 64); m3 += __shfl_xor(m3, 32, 64);
  wacc += __shfl_xor(wacc, 32, 64);

  float rl = 1.f / wacc;
  float v0 = m0 * rl + getf(bias, ch + 0, f0);
  float v1 = m1 * rl + getf(bias, ch + 1, f0);
  float v2 = m2 * rl + getf(bias, ch + 2, f0);
  float v3 = m3 * rl + getf(bias, ch + 3, f0);

  float mu = bfly_sum(v0 + v1 + v2 + v3) * (1.f / 256.f);
  float d0 = v0 - mu, d1 = v1 - mu, d2 = v2 - mu, d3 = v3 - mu;
  float var = bfly_sum(d0*d0 + d1*d1 + d2*d2 + d3*d3) * (1.f / 256.f);
  float rs = rsqrtf(var + 1e-5f);

  if (es == 0){
    bf16x4 o;
    float y;
    y = d0 * rs * getf(gamma, ch+0, f0) + getf(beta, ch+0, f0); o[0] = (__bf16)y;
    y = d1 * rs * getf(gamma, ch+1, f0) + getf(beta, ch+1, f0); o[1] = (__bf16)y;
    y = d2 * rs * getf(gamma, ch+2, f0) + getf(beta, ch+2, f0); o[2] = (__bf16)y;
    y = d3 * rs * getf(gamma, ch+3, f0) + getf(beta, ch+3, f0); o[3] = (__bf16)y;
    *(bf16x4*)(outb + (size_t)i * 128 + ch) = o;
  }
}

// ---------------- launch ----------------
extern "C" void kernel_launch(void* const* d_in, const int* in_sizes, int n_in,
                              void* d_out, int out_size, void* d_ws, size_t ws_size,
                              hipStream_t stream)
{
  const void* x   = d_in[0];
  const void* ei  = d_in[1];
  const void* Wp  = d_in[2];
  const void* bp  = d_in[3];
  const void* W0  = d_in[4];
  const void* as0 = d_in[5];
  const void* ad0 = d_in[6];
  const void* b0  = d_in[7];
  const void* W1  = d_in[8];
  const void* as1 = d_in[9];
  const void* ad1 = d_in[10];
  const void* b1  = d_in[11];
  const void* g0  = d_in[12];
  const void* be0 = d_in[13];
  const void* g1  = d_in[14];
  const void* be1 = d_in[15];
  const void* Wo  = d_in[16];
  const void* bo  = d_in[17];
  float* outp = (float*)d_out;

  const int n = in_sizes[0] / 256;   // 50000
  const int E = in_sizes[1] / 2;     // 800000

  char* w = (char*)d_ws;
  size_t SZ = (size_t)n * 256 * sizeof(float);
  __hip_bfloat16* h_bf  = (__hip_bfloat16*)w;             // h -> h1 -> h2 (bf16)
  __hip_bfloat16* xw_bf = (__hip_bfloat16*)(w + SZ / 2);  // xw0 -> xw1 (bf16)
  char* p = w + SZ;
  int* flags = (int*)p; p += 64;
  float* als0 = (float*)p; p += (size_t)n * 4 * sizeof(float);
  float* ald0 = (float*)p; p += (size_t)n * 4 * sizeof(float);
  float* als1 = (float*)p; p += (size_t)n * sizeof(float);
  float* ald1 = (float*)p; p += (size_t)n * sizeof(float);
  int* cnt    = (int*)p; p += (size_t)n * sizeof(int);
  int* hist   = (int*)p; p += 256 * sizeof(int);
  int* binpos = (int*)p; p += 256 * sizeof(int);
  int* order  = (int*)p; p += (size_t)n * sizeof(int);
  int* offb   = (int*)p; p += (size_t)(n + 4) * sizeof(int);
  int* pos    = (int*)p; p += (size_t)n * sizeof(int);
  int* bsrc   = (int*)p; p += (size_t)E * sizeof(int);
  p = (char*)(((uintptr_t)p + 15) & ~(uintptr_t)15);
  __hip_bfloat16* bt_p = (__hip_bfloat16*)p; p += (size_t)256 * 256 * 2;
  __hip_bfloat16* bt_0 = (__hip_bfloat16*)p; p += (size_t)256 * 256 * 2;
  __hip_bfloat16* bt_1 = (__hip_bfloat16*)p; p += (size_t)128 * 256 * 2;
  __hip_bfloat16* bt_o = (__hip_bfloat16*)p; p += (size_t)128 * 128 * 2;

  detect_kernel<<<1, 256, 0, stream>>>(x, ei, flags);

  transpose_all_kernel<<<704, 256, 0, stream>>>(Wp, W0, W1, Wo, flags, bt_p, bt_0, bt_1, bt_o);

  (void)hipMemsetAsync(cnt, 0, ((size_t)n + 256) * sizeof(int), stream);  // cnt + hist
  count_kernel<<<(E + 255) / 256, 256, 0, stream>>>(ei, E, n, flags, cnt);
  scan_kernel<<<1, 1024, 0, stream>>>(cnt, offb, pos, n);
  int gnn = (n + 255) / 256;
  deghist_kernel<<<gnn, 256, 0, stream>>>(cnt, n, hist);
  degscan_kernel<<<1, 256, 0, stream>>>(hist, binpos);
  degscatter_kernel<<<gnn, 256, 0, stream>>>(cnt, n, binpos, order);
  fill_kernel<<<(E + 255) / 256, 256, 0, stream>>>(ei, E, n, flags, pos, bsrc);

  int gm = (n + 127) / 128;
  int gn4 = (n + 3) / 4;

  // h = relu(x @ Wp + bp) -> bf16 only
  gemm_direct_kernel<1, false, true, true, true, false, 0><<<dim3(gm, 2), 256, 0, stream>>>(
      x, bt_p, bp, nullptr, nullptr, flags, nullptr, h_bf, nullptr, nullptr, n, 256, 256);
  // xw0 = h @ W0 (bf16) + fused als0/ald0
  gemm_direct_kernel<0, false, true, false, false, false, 1><<<dim3(gm, 2), 256, 0, stream>>>(
      h_bf, bt_0, nullptr, as0, ad0, flags, nullptr, xw_bf, als0, ald0, n, 256, 256);
  // layer-0 aggregate + b0 + LN + residual(bf16) + relu -> h1 in-place
  gather0_kernel<<<gn4, 256, 0, stream>>>(xw_bf, als0, ald0, bsrc, offb, order, b0, g0, be0,
                                          flags, h_bf, n);
  // xw1 = h1 @ W1 (bf16, n x 128) + fused als1/ald1
  gemm_direct_kernel<0, false, true, false, false, false, 2><<<dim3(gm, 1), 256, 0, stream>>>(
      h_bf, bt_1, nullptr, as1, ad1, flags, nullptr, xw_bf, als1, ald1, n, 128, 256);
  // layer-1 aggregate + b1 + LN -> h2 (bf16, into h_bf)
  gather1_kernel<<<gn4, 256, 0, stream>>>(xw_bf, als1, ald1, bsrc, offb, order, b1, g1, be1,
                                          flags, h_bf, n);
  // out = l2normalize(h2 @ Wo + bo), fused epilogue, direct to output
  gemm_direct_kernel<0, true, false, false, true, true, 0><<<dim3(gm, 1), 256, 0, stream>>>(
      h_bf, bt_o, bo, nullptr, nullptr, flags, outp, nullptr, nullptr, nullptr, n, 128, 128);
}

// Round 6
// 543.710 us; speedup vs baseline: 1.5113x; 1.5113x over previous
//
#include <hip/hip_runtime.h>
#include <hip/hip_bf16.h>

typedef __bf16 bf16x8 __attribute__((ext_vector_type(8)));
typedef __bf16 bf16x4 __attribute__((ext_vector_type(4)));
typedef __bf16 bf16x2 __attribute__((ext_vector_type(2)));
typedef float f32x4 __attribute__((ext_vector_type(4)));
typedef unsigned u32x4 __attribute__((ext_vector_type(4)));

// ---------------- dtype-robust load helpers ----------------
__device__ __forceinline__ float getf(const void* p, size_t i, int isf32){
  return isf32 ? ((const float*)p)[i]
               : __bfloat162float(((const __hip_bfloat16*)p)[i]);
}
__device__ __forceinline__ int getedge(const void* p, long long idx, int is64, int n){
  long long v = is64 ? ((const long long*)p)[idx] : (long long)((const int*)p)[idx];
  v = v < 0 ? 0 : (v >= n ? (long long)(n - 1) : v);
  return (int)v;
}

__device__ __forceinline__ float bfly_sum(float v){
#pragma unroll
  for (int m = 32; m > 0; m >>= 1) v += __shfl_xor(v, m, 64);
  return v;
}

__device__ __forceinline__ float bf_lo(unsigned u){ return __uint_as_float(u << 16); }
__device__ __forceinline__ float bf_hi(unsigned u){ return __uint_as_float(u & 0xffff0000u); }

// ---------------- runtime dtype detection ----------------
__global__ __launch_bounds__(256) void detect_kernel(const void* x, const void* ei,
                                                     int* flags){
  __shared__ int cnt_sane, cnt_odd;
  int t = threadIdx.x;
  if (t == 0){ cnt_sane = 0; cnt_odd = 0; }
  __syncthreads();
  int sane = 0;
  for (int i = t; i < 4096; i += 256){
    float v = __bfloat162float(((const __hip_bfloat16*)x)[i]);
    if (fabsf(v) < 16.f) sane++;
  }
  atomicAdd(&cnt_sane, sane);
  int odd = 0;
  for (int i = t; i < 512; i += 256){
    if (((const int*)ei)[2 * i + 1] != 0) odd++;
  }
  atomicAdd(&cnt_odd, odd);
  __syncthreads();
  if (t == 0){
    flags[0] = (cnt_sane < 3900) ? 1 : 0;  // 1 => float inputs are fp32
    flags[1] = (cnt_odd == 0) ? 1 : 0;     // 1 => edge_index is int64
  }
}

// ---------------- graph bucketing ----------------
__global__ __launch_bounds__(256) void count_kernel(const void* __restrict__ ei, long long E,
                                                    int n, const int* __restrict__ flags,
                                                    int* __restrict__ cnt){
  int i = blockIdx.x * blockDim.x + threadIdx.x;
  if (i < E){
    int d = getedge(ei, E + i, flags[1], n);
    atomicAdd(&cnt[d], 1);
  }
}

// 4x-vectorized single-block scan
__global__ __launch_bounds__(1024) void scan_kernel(const int* __restrict__ cnt, int* __restrict__ off,
                                                    int* __restrict__ pos, int n){
  __shared__ int wsum[16];
  __shared__ int carry_s;
  int tid = threadIdx.x, lane = tid & 63, wv = tid >> 6;
  if (tid == 0) carry_s = 0;
  __syncthreads();
  for (int base = 0; base < n; base += 4096){
    int i0 = base + tid * 4;
    int v0 = 0, v1 = 0, v2 = 0, v3 = 0;
    if (i0 + 3 < n){
      int4 q = *(const int4*)(cnt + i0);
      v0 = q.x; v1 = q.y; v2 = q.z; v3 = q.w;
    } else {
      if (i0 < n)     v0 = cnt[i0];
      if (i0 + 1 < n) v1 = cnt[i0 + 1];
      if (i0 + 2 < n) v2 = cnt[i0 + 2];
      if (i0 + 3 < n) v3 = cnt[i0 + 3];
    }
    int s4 = v0 + v1 + v2 + v3;
    int s = s4;
#pragma unroll
    for (int o = 1; o < 64; o <<= 1){ int t = __shfl_up(s, o, 64); if (lane >= o) s += t; }
    if (lane == 63) wsum[wv] = s;
    __syncthreads();
    int wo = 0;
    for (int w = 0; w < wv; w++) wo += wsum[w];
    int carry = carry_s;
    int e0 = carry + wo + s - s4;
    if (i0 + 3 < n){
      int4 o4; o4.x = e0; o4.y = e0 + v0; o4.z = e0 + v0 + v1; o4.w = e0 + v0 + v1 + v2;
      *(int4*)(off + i0) = o4;
      *(int4*)(pos + i0) = o4;
    } else {
      if (i0 < n)     { off[i0] = e0;               pos[i0] = e0; }
      if (i0 + 1 < n) { off[i0+1] = e0+v0;          pos[i0+1] = e0+v0; }
      if (i0 + 2 < n) { off[i0+2] = e0+v0+v1;       pos[i0+2] = e0+v0+v1; }
      if (i0 + 3 < n) { off[i0+3] = e0+v0+v1+v2;    pos[i0+3] = e0+v0+v1+v2; }
    }
    __syncthreads();
    if (tid == 0){
      int tot = 0;
      for (int w = 0; w < 16; w++) tot += wsum[w];
      carry_s = carry + tot;
    }
    __syncthreads();
  }
  if (tid == 0) off[n] = carry_s;
}

__global__ __launch_bounds__(256) void fill_kernel(const void* __restrict__ ei, long long E,
                                                   int n, const int* __restrict__ flags,
                                                   int* __restrict__ pos, int* __restrict__ bsrc){
  int i = blockIdx.x * blockDim.x + threadIdx.x;
  if (i < E){
    int d = getedge(ei, E + i, flags[1], n);
    int s = getedge(ei, i, flags[1], n);
    int p = atomicAdd(&pos[d], 1);
    bsrc[p] = s;
  }
}

// ---------------- fused weight pre-transpose: Bt[N][K] (bf16) = W[K][N] ----------------
__global__ __launch_bounds__(256) void transpose_all_kernel(
    const void* __restrict__ Wp, const void* __restrict__ W0,
    const void* __restrict__ W1, const void* __restrict__ Wo,
    const int* __restrict__ flags,
    __hip_bfloat16* __restrict__ btp, __hip_bfloat16* __restrict__ bt0,
    __hip_bfloat16* __restrict__ bt1, __hip_bfloat16* __restrict__ bto)
{
  int f0 = flags[0];
  int o = blockIdx.x * 256 + threadIdx.x;
  const void* W; __hip_bfloat16* B; int K, N, loc;
  if (o < 65536)       { W = Wp; B = btp; K = 256; N = 256; loc = o; }
  else if (o < 131072) { W = W0; B = bt0; K = 256; N = 256; loc = o - 65536; }
  else if (o < 163840) { W = W1; B = bt1; K = 256; N = 128; loc = o - 131072; }
  else if (o < 180224) { W = Wo; B = bto; K = 128; N = 128; loc = o - 163840; }
  else return;
  int nn = loc / K, kk = loc - nn * K;
  B[loc] = __float2bfloat16(getf(W, (size_t)kk * N + nn, f0));
}

// ---------------- LDS-free direct-fragment MFMA GEMM ----------------
__device__ __forceinline__ bf16x8 pk8(f32x4 u, f32x4 w){
  bf16x8 r;
  r[0] = (__bf16)u.x; r[1] = (__bf16)u.y; r[2] = (__bf16)u.z; r[3] = (__bf16)u.w;
  r[4] = (__bf16)w.x; r[5] = (__bf16)w.y; r[6] = (__bf16)w.z; r[7] = (__bf16)w.w;
  return r;
}

template<int AMODE, bool OUTF, bool OUTB, bool RELU, bool BIAS, bool NORM, int ALMODE>
__global__ __launch_bounds__(256) void gemm_direct_kernel(
    const void* __restrict__ A, const __hip_bfloat16* __restrict__ Bt,
    const void* __restrict__ bias, const void* __restrict__ a_s, const void* __restrict__ a_d,
    const int* __restrict__ flags,
    float* __restrict__ Cf, __hip_bfloat16* __restrict__ Cb,
    float* __restrict__ als, float* __restrict__ ald,
    int M, int N, int K)
{
  const int f0 = flags[0];
  const bool af32 = (AMODE == 1) && (f0 != 0);
  int t = threadIdx.x;
  int wave = t >> 6, lane = t & 63;
  int q = lane >> 4, mi = lane & 15;
  int bm = blockIdx.x * 128 + wave * 32;
  int bn = blockIdx.y * 128;

  int r0 = min(bm + mi, M - 1);
  int r1 = min(bm + 16 + mi, M - 1);

  f32x4 acc[2][8] = {};

  if (af32){
    const float* Af = (const float*)A;
    const float* p0 = Af + (size_t)r0 * K + q * 8;
    const float* p1 = Af + (size_t)r1 * K + q * 8;
#pragma unroll 2
    for (int k0 = 0; k0 < K; k0 += 32){
      f32x4 u0 = *(const f32x4*)(p0 + k0);
      f32x4 w0 = *(const f32x4*)(p0 + k0 + 4);
      f32x4 u1 = *(const f32x4*)(p1 + k0);
      f32x4 w1 = *(const f32x4*)(p1 + k0 + 4);
      bf16x8 a0 = pk8(u0, w0);
      bf16x8 a1 = pk8(u1, w1);
#pragma unroll
      for (int nt = 0; nt < 8; nt++){
        bf16x8 b = *(const bf16x8*)(Bt + (size_t)(bn + nt * 16 + mi) * K + k0 + q * 8);
        acc[0][nt] = __builtin_amdgcn_mfma_f32_16x16x32_bf16(a0, b, acc[0][nt], 0, 0, 0);
        acc[1][nt] = __builtin_amdgcn_mfma_f32_16x16x32_bf16(a1, b, acc[1][nt], 0, 0, 0);
      }
    }
  } else {
    const __hip_bfloat16* Ab = (const __hip_bfloat16*)A;
    const __hip_bfloat16* p0 = Ab + (size_t)r0 * K + q * 8;
    const __hip_bfloat16* p1 = Ab + (size_t)r1 * K + q * 8;
#pragma unroll 2
    for (int k0 = 0; k0 < K; k0 += 32){
      bf16x8 a0 = *(const bf16x8*)(p0 + k0);
      bf16x8 a1 = *(const bf16x8*)(p1 + k0);
#pragma unroll
      for (int nt = 0; nt < 8; nt++){
        bf16x8 b = *(const bf16x8*)(Bt + (size_t)(bn + nt * 16 + mi) * K + k0 + q * 8);
        acc[0][nt] = __builtin_amdgcn_mfma_f32_16x16x32_bf16(a0, b, acc[0][nt], 0, 0, 0);
        acc[1][nt] = __builtin_amdgcn_mfma_f32_16x16x32_bf16(a1, b, acc[1][nt], 0, 0, 0);
      }
    }
  }

  float bv[8], asv[8], adv[8];
  if (BIAS){
#pragma unroll
    for (int nt = 0; nt < 8; nt++) bv[nt] = getf(bias, bn + nt * 16 + mi, f0);
  }
  if (ALMODE != 0){
#pragma unroll
    for (int nt = 0; nt < 8; nt++){
      asv[nt] = getf(a_s, bn + nt * 16 + mi, f0);
      adv[nt] = getf(a_d, bn + nt * 16 + mi, f0);
    }
  }
#pragma unroll
  for (int mt = 0; mt < 2; mt++){
#pragma unroll
    for (int r = 0; r < 4; r++){
      int row = bm + mt * 16 + q * 4 + r;
      float vv[8];
#pragma unroll
      for (int nt = 0; nt < 8; nt++){
        float v = acc[mt][nt][r];
        if (BIAS) v += bv[nt];
        if (RELU) v = fmaxf(v, 0.f);
        vv[nt] = v;
      }
      if (NORM){
        float ss = 0.f;
#pragma unroll
        for (int nt = 0; nt < 8; nt++) ss += vv[nt] * vv[nt];
        ss += __shfl_xor(ss, 1, 64);
        ss += __shfl_xor(ss, 2, 64);
        ss += __shfl_xor(ss, 4, 64);
        ss += __shfl_xor(ss, 8, 64);
        float inv = 1.f / fmaxf(sqrtf(ss), 1e-12f);
#pragma unroll
        for (int nt = 0; nt < 8; nt++) vv[nt] *= inv;
      }
      if (ALMODE == 1){
        float ps0 = 0.f, pd0 = 0.f, ps1 = 0.f, pd1 = 0.f;
#pragma unroll
        for (int nt = 0; nt < 4; nt++){ ps0 += vv[nt] * asv[nt]; pd0 += vv[nt] * adv[nt]; }
#pragma unroll
        for (int nt = 4; nt < 8; nt++){ ps1 += vv[nt] * asv[nt]; pd1 += vv[nt] * adv[nt]; }
#pragma unroll
        for (int m = 1; m < 16; m <<= 1){
          ps0 += __shfl_xor(ps0, m, 64); pd0 += __shfl_xor(pd0, m, 64);
          ps1 += __shfl_xor(ps1, m, 64); pd1 += __shfl_xor(pd1, m, 64);
        }
        if ((lane & 15) == 0 && row < M){
          int h0 = blockIdx.y * 2;
          als[(size_t)row * 4 + h0]     = ps0; ald[(size_t)row * 4 + h0]     = pd0;
          als[(size_t)row * 4 + h0 + 1] = ps1; ald[(size_t)row * 4 + h0 + 1] = pd1;
        }
      } else if (ALMODE == 2){
        float ps = 0.f, pd = 0.f;
#pragma unroll
        for (int nt = 0; nt < 8; nt++){ ps += vv[nt] * asv[nt]; pd += vv[nt] * adv[nt]; }
#pragma unroll
        for (int m = 1; m < 16; m <<= 1){
          ps += __shfl_xor(ps, m, 64); pd += __shfl_xor(pd, m, 64);
        }
        if ((lane & 15) == 0 && row < M){ als[row] = ps; ald[row] = pd; }
      }
      if (row < M){
#pragma unroll
        for (int nt = 0; nt < 8; nt++){
          int col = bn + nt * 16 + mi;
          size_t idx = (size_t)row * N + col;
          if (OUTF) Cf[idx] = vv[nt];
          if (OUTB) Cb[idx] = __float2bfloat16(vv[nt]);
        }
      }
    }
  }
}

#define UFMA8(U, W) do { \
  m0 += (W) * bf_lo((U).x); m1 += (W) * bf_hi((U).x); \
  m2 += (W) * bf_lo((U).y); m3 += (W) * bf_hi((U).y); \
  m4 += (W) * bf_lo((U).z); m5 += (W) * bf_hi((U).z); \
  m6 += (W) * bf_lo((U).w); m7 += (W) * bf_hi((U).w); \
} while (0)

#define UFMA4(U, W) do { \
  m0 += (W) * bf_lo((U).x); m1 += (W) * bf_hi((U).x); \
  m2 += (W) * bf_lo((U).y); m3 += (W) * bf_hi((U).y); \
} while (0)

// ---------------- gather0: wave-per-node, half-wave-per-edge, H=4, C=64 ----------------
// lanes 0-31 process even edge slots, lanes 32-63 odd slots; each sub-lane owns
// 8 channels (uint4 = 16B load). Denominator/macc fold with one shfl_xor(32).
__global__ __launch_bounds__(256) void gather0_kernel(
    const __hip_bfloat16* __restrict__ xw, const float* __restrict__ als, const float* __restrict__ ald,
    const int* __restrict__ bsrc, const int* __restrict__ off,
    const void* __restrict__ bias, const void* __restrict__ gamma,
    const void* __restrict__ beta, const int* __restrict__ flags,
    __hip_bfloat16* __restrict__ hbuf, int n)
{
  int f0 = flags[0];
  int t = threadIdx.x, wv = t >> 6, lane = t & 63;
  int i = blockIdx.x * 4 + wv;
  if (i >= n) return;
  int es = lane >> 5;          // 0/1: which edge of a pair
  int sl = lane & 31;
  int ch = sl * 8;             // 8 channels per sub-lane
  int head = sl >> 3;          // 0..3
  int e0 = off[i], jend = off[i + 1];

  float m0=0.f,m1=0.f,m2=0.f,m3=0.f,m4=0.f,m5=0.f,m6=0.f,m7=0.f;
  float aldi = ald[(size_t)i * 4 + head];

  float se = als[(size_t)i * 4 + head] + aldi;
  se = (se > 0.f) ? se : 0.2f * se;
  float eself = __expf(se);
  float wacc = 0.f;
  if (es == 0){
    uint4 u = *(const uint4*)(xw + (size_t)i * 256 + ch);
    UFMA8(u, eself);
    wacc = eself;
  }

  // 8 edges per iteration (4 per half-wave), clamped pipeline
  for (int j = e0 + es; j < jend; j += 8){
    int j1 = j + 2, j2 = j + 4, j3 = j + 6;
    int c1 = min(j1, jend - 1), c2 = min(j2, jend - 1), c3 = min(j3, jend - 1);
    int s0 = bsrc[j], s1 = bsrc[c1], s2 = bsrc[c2], s3 = bsrc[c3];
    float l0 = als[(size_t)s0 * 4 + head] + aldi;
    float l1 = als[(size_t)s1 * 4 + head] + aldi;
    float l2 = als[(size_t)s2 * 4 + head] + aldi;
    float l3 = als[(size_t)s3 * 4 + head] + aldi;
    l0 = (l0 > 0.f) ? l0 : 0.2f * l0;
    l1 = (l1 > 0.f) ? l1 : 0.2f * l1;
    l2 = (l2 > 0.f) ? l2 : 0.2f * l2;
    l3 = (l3 > 0.f) ? l3 : 0.2f * l3;
    float w0 = __expf(l0);
    float w1 = (j1 < jend) ? __expf(l1) : 0.f;
    float w2 = (j2 < jend) ? __expf(l2) : 0.f;
    float w3 = (j3 < jend) ? __expf(l3) : 0.f;
    uint4 U0 = *(const uint4*)(xw + (size_t)s0 * 256 + ch);
    uint4 U1 = *(const uint4*)(xw + (size_t)s1 * 256 + ch);
    uint4 U2 = *(const uint4*)(xw + (size_t)s2 * 256 + ch);
    uint4 U3 = *(const uint4*)(xw + (size_t)s3 * 256 + ch);
    wacc += w0 + w1 + w2 + w3;
    UFMA8(U0, w0); UFMA8(U1, w1); UFMA8(U2, w2); UFMA8(U3, w3);
  }

  // fold edge halves (lane^32 holds same channels, other edges)
  m0 += __shfl_xor(m0, 32, 64); m1 += __shfl_xor(m1, 32, 64);
  m2 += __shfl_xor(m2, 32, 64); m3 += __shfl_xor(m3, 32, 64);
  m4 += __shfl_xor(m4, 32, 64); m5 += __shfl_xor(m5, 32, 64);
  m6 += __shfl_xor(m6, 32, 64); m7 += __shfl_xor(m7, 32, 64);
  wacc += __shfl_xor(wacc, 32, 64);

  float rl = 1.f / wacc;
  float v0 = m0 * rl + getf(bias, ch + 0, f0);
  float v1 = m1 * rl + getf(bias, ch + 1, f0);
  float v2 = m2 * rl + getf(bias, ch + 2, f0);
  float v3 = m3 * rl + getf(bias, ch + 3, f0);
  float v4 = m4 * rl + getf(bias, ch + 4, f0);
  float v5 = m5 * rl + getf(bias, ch + 5, f0);
  float v6 = m6 * rl + getf(bias, ch + 6, f0);
  float v7 = m7 * rl + getf(bias, ch + 7, f0);

  // LN over 256 ch; both halves duplicate -> butterfly total is 2x
  float mu = bfly_sum(v0+v1+v2+v3+v4+v5+v6+v7) * (1.f / 512.f);
  float d0=v0-mu,d1=v1-mu,d2=v2-mu,d3=v3-mu,d4=v4-mu,d5=v5-mu,d6=v6-mu,d7=v7-mu;
  float var = bfly_sum(d0*d0+d1*d1+d2*d2+d3*d3+d4*d4+d5*d5+d6*d6+d7*d7) * (1.f / 512.f);
  float rs = rsqrtf(var + 1e-5f);

  if (es == 0){
    u32x4 rbu = __builtin_nontemporal_load((const u32x4*)(hbuf + (size_t)i * 256 + ch));
    bf16x8 rb = __builtin_bit_cast(bf16x8, rbu);
    bf16x8 o;
    float y;
    y = d0 * rs * getf(gamma, ch+0, f0) + getf(beta, ch+0, f0) + (float)rb[0]; o[0] = (__bf16)fmaxf(y, 0.f);
    y = d1 * rs * getf(gamma, ch+1, f0) + getf(beta, ch+1, f0) + (float)rb[1]; o[1] = (__bf16)fmaxf(y, 0.f);
    y = d2 * rs * getf(gamma, ch+2, f0) + getf(beta, ch+2, f0) + (float)rb[2]; o[2] = (__bf16)fmaxf(y, 0.f);
    y = d3 * rs * getf(gamma, ch+3, f0) + getf(beta, ch+3, f0) + (float)rb[3]; o[3] = (__bf16)fmaxf(y, 0.f);
    y = d4 * rs * getf(gamma, ch+4, f0) + getf(beta, ch+4, f0) + (float)rb[4]; o[4] = (__bf16)fmaxf(y, 0.f);
    y = d5 * rs * getf(gamma, ch+5, f0) + getf(beta, ch+5, f0) + (float)rb[5]; o[5] = (__bf16)fmaxf(y, 0.f);
    y = d6 * rs * getf(gamma, ch+6, f0) + getf(beta, ch+6, f0) + (float)rb[6]; o[6] = (__bf16)fmaxf(y, 0.f);
    y = d7 * rs * getf(gamma, ch+7, f0) + getf(beta, ch+7, f0) + (float)rb[7]; o[7] = (__bf16)fmaxf(y, 0.f);
    *(bf16x8*)(hbuf + (size_t)i * 256 + ch) = o;
  }
}

// ---------------- gather1: wave-per-node, half-wave-per-edge, H=1, C=128 ----------------
__global__ __launch_bounds__(256) void gather1_kernel(
    const __hip_bfloat16* __restrict__ xw, const float* __restrict__ als, const float* __restrict__ ald,
    const int* __restrict__ bsrc, const int* __restrict__ off,
    const void* __restrict__ bias, const void* __restrict__ gamma,
    const void* __restrict__ beta, const int* __restrict__ flags,
    __hip_bfloat16* __restrict__ outb, int n)
{
  int f0 = flags[0];
  int t = threadIdx.x, wv = t >> 6, lane = t & 63;
  int i = blockIdx.x * 4 + wv;
  if (i >= n) return;
  int es = lane >> 5;
  int sl = lane & 31;
  int ch = sl * 4;             // 4 channels per sub-lane
  int e0 = off[i], jend = off[i + 1];

  float m0=0.f,m1=0.f,m2=0.f,m3=0.f;
  float aldi = ald[i];
  float se = als[i] + aldi;
  se = (se > 0.f) ? se : 0.2f * se;
  float eself = __expf(se);
  float wacc = 0.f;
  if (es == 0){
    uint2 u = *(const uint2*)(xw + (size_t)i * 128 + ch);
    UFMA4(u, eself);
    wacc = eself;
  }

  for (int j = e0 + es; j < jend; j += 8){
    int j1 = j + 2, j2 = j + 4, j3 = j + 6;
    int c1 = min(j1, jend - 1), c2 = min(j2, jend - 1), c3 = min(j3, jend - 1);
    int s0 = bsrc[j], s1 = bsrc[c1], s2 = bsrc[c2], s3 = bsrc[c3];
    float l0 = als[s0] + aldi, l1 = als[s1] + aldi, l2 = als[s2] + aldi, l3 = als[s3] + aldi;
    l0 = (l0 > 0.f) ? l0 : 0.2f * l0;
    l1 = (l1 > 0.f) ? l1 : 0.2f * l1;
    l2 = (l2 > 0.f) ? l2 : 0.2f * l2;
    l3 = (l3 > 0.f) ? l3 : 0.2f * l3;
    float w0 = __expf(l0);
    float w1 = (j1 < jend) ? __expf(l1) : 0.f;
    float w2 = (j2 < jend) ? __expf(l2) : 0.f;
    float w3 = (j3 < jend) ? __expf(l3) : 0.f;
    uint2 U0 = *(const uint2*)(xw + (size_t)s0 * 128 + ch);
    uint2 U1 = *(const uint2*)(xw + (size_t)s1 * 128 + ch);
    uint2 U2 = *(const uint2*)(xw + (size_t)s2 * 128 + ch);
    uint2 U3 = *(const uint2*)(xw + (size_t)s3 * 128 + ch);
    wacc += w0 + w1 + w2 + w3;
    UFMA4(U0, w0); UFMA4(U1, w1); UFMA4(U2, w2); UFMA4(U3, w3);
  }

  m0 += __shfl_xor(m0, 32, 64); m1 += __shfl_xor(m1, 32, 64);
  m2 += __shfl_xor(m2, 32, 64); m3 += __shfl_xor(m3, 32, 64);
  wacc += __shfl_xor(wacc, 32, 64);

  float rl = 1.f / wacc;
  float v0 = m0 * rl + getf(bias, ch + 0, f0);
  float v1 = m1 * rl + getf(bias, ch + 1, f0);
  float v2 = m2 * rl + getf(bias, ch + 2, f0);
  float v3 = m3 * rl + getf(bias, ch + 3, f0);

  float mu = bfly_sum(v0 + v1 + v2 + v3) * (1.f / 256.f);
  float d0 = v0 - mu, d1 = v1 - mu, d2 = v2 - mu, d3 = v3 - mu;
  float var = bfly_sum(d0*d0 + d1*d1 + d2*d2 + d3*d3) * (1.f / 256.f);
  float rs = rsqrtf(var + 1e-5f);

  if (es == 0){
    bf16x4 o;
    float y;
    y = d0 * rs * getf(gamma, ch+0, f0) + getf(beta, ch+0, f0); o[0] = (__bf16)y;
    y = d1 * rs * getf(gamma, ch+1, f0) + getf(beta, ch+1, f0); o[1] = (__bf16)y;
    y = d2 * rs * getf(gamma, ch+2, f0) + getf(beta, ch+2, f0); o[2] = (__bf16)y;
    y = d3 * rs * getf(gamma, ch+3, f0) + getf(beta, ch+3, f0); o[3] = (__bf16)y;
    *(bf16x4*)(outb + (size_t)i * 128 + ch) = o;
  }
}

// ---------------- launch ----------------
extern "C" void kernel_launch(void* const* d_in, const int* in_sizes, int n_in,
                              void* d_out, int out_size, void* d_ws, size_t ws_size,
                              hipStream_t stream)
{
  const void* x   = d_in[0];
  const void* ei  = d_in[1];
  const void* Wp  = d_in[2];
  const void* bp  = d_in[3];
  const void* W0  = d_in[4];
  const void* as0 = d_in[5];
  const void* ad0 = d_in[6];
  const void* b0  = d_in[7];
  const void* W1  = d_in[8];
  const void* as1 = d_in[9];
  const void* ad1 = d_in[10];
  const void* b1  = d_in[11];
  const void* g0  = d_in[12];
  const void* be0 = d_in[13];
  const void* g1  = d_in[14];
  const void* be1 = d_in[15];
  const void* Wo  = d_in[16];
  const void* bo  = d_in[17];
  float* outp = (float*)d_out;

  const int n = in_sizes[0] / 256;   // 50000
  const int E = in_sizes[1] / 2;     // 800000

  char* w = (char*)d_ws;
  size_t SZ = (size_t)n * 256 * sizeof(float);
  __hip_bfloat16* h_bf  = (__hip_bfloat16*)w;             // h -> h1 -> h2 (bf16)
  __hip_bfloat16* xw_bf = (__hip_bfloat16*)(w + SZ / 2);  // xw0 -> xw1 (bf16)
  char* p = w + SZ;
  int* flags = (int*)p; p += 64;
  float* als0 = (float*)p; p += (size_t)n * 4 * sizeof(float);
  float* ald0 = (float*)p; p += (size_t)n * 4 * sizeof(float);
  float* als1 = (float*)p; p += (size_t)n * sizeof(float);
  float* ald1 = (float*)p; p += (size_t)n * sizeof(float);
  int* cnt    = (int*)p; p += (size_t)n * sizeof(int);
  int* offb   = (int*)p; p += (size_t)(n + 4) * sizeof(int);
  int* pos    = (int*)p; p += (size_t)n * sizeof(int);
  int* bsrc   = (int*)p; p += (size_t)E * sizeof(int);
  p = (char*)(((uintptr_t)p + 15) & ~(uintptr_t)15);
  __hip_bfloat16* bt_p = (__hip_bfloat16*)p; p += (size_t)256 * 256 * 2;
  __hip_bfloat16* bt_0 = (__hip_bfloat16*)p; p += (size_t)256 * 256 * 2;
  __hip_bfloat16* bt_1 = (__hip_bfloat16*)p; p += (size_t)128 * 256 * 2;
  __hip_bfloat16* bt_o = (__hip_bfloat16*)p; p += (size_t)128 * 128 * 2;

  detect_kernel<<<1, 256, 0, stream>>>(x, ei, flags);

  transpose_all_kernel<<<704, 256, 0, stream>>>(Wp, W0, W1, Wo, flags, bt_p, bt_0, bt_1, bt_o);

  (void)hipMemsetAsync(cnt, 0, (size_t)n * sizeof(int), stream);
  count_kernel<<<(E + 255) / 256, 256, 0, stream>>>(ei, E, n, flags, cnt);
  scan_kernel<<<1, 1024, 0, stream>>>(cnt, offb, pos, n);
  fill_kernel<<<(E + 255) / 256, 256, 0, stream>>>(ei, E, n, flags, pos, bsrc);

  int gm = (n + 127) / 128;
  int gn4 = (n + 3) / 4;

  // h = relu(x @ Wp + bp) -> bf16 only
  gemm_direct_kernel<1, false, true, true, true, false, 0><<<dim3(gm, 2), 256, 0, stream>>>(
      x, bt_p, bp, nullptr, nullptr, flags, nullptr, h_bf, nullptr, nullptr, n, 256, 256);
  // xw0 = h @ W0 (bf16) + fused als0/ald0
  gemm_direct_kernel<0, false, true, false, false, false, 1><<<dim3(gm, 2), 256, 0, stream>>>(
      h_bf, bt_0, nullptr, as0, ad0, flags, nullptr, xw_bf, als0, ald0, n, 256, 256);
  // layer-0 aggregate + b0 + LN + residual(bf16) + relu -> h1 in-place
  gather0_kernel<<<gn4, 256, 0, stream>>>(xw_bf, als0, ald0, bsrc, offb, b0, g0, be0,
                                          flags, h_bf, n);
  // xw1 = h1 @ W1 (bf16, n x 128) + fused als1/ald1
  gemm_direct_kernel<0, false, true, false, false, false, 2><<<dim3(gm, 1), 256, 0, stream>>>(
      h_bf, bt_1, nullptr, as1, ad1, flags, nullptr, xw_bf, als1, ald1, n, 128, 256);
  // layer-1 aggregate + b1 + LN -> h2 (bf16, into h_bf)
  gather1_kernel<<<gn4, 256, 0, stream>>>(xw_bf, als1, ald1, bsrc, offb, b1, g1, be1,
                                          flags, h_bf, n);
  // out = l2normalize(h2 @ Wo + bo), fused epilogue, direct to output
  gemm_direct_kernel<0, true, false, false, true, true, 0><<<dim3(gm, 1), 256, 0, stream>>>(
      h_bf, bt_o, bo, nullptr, nullptr, flags, outp, nullptr, nullptr, nullptr, n, 128, 128);
}

// Round 7
// 485.050 us; speedup vs baseline: 1.6941x; 1.1209x over previous
//
#include <hip/hip_runtime.h>
#include <hip/hip_bf16.h>

typedef __bf16 bf16x8 __attribute__((ext_vector_type(8)));
typedef __bf16 bf16x4 __attribute__((ext_vector_type(4)));
typedef __bf16 bf16x2 __attribute__((ext_vector_type(2)));
typedef float f32x4 __attribute__((ext_vector_type(4)));

// ---------------- dtype-robust load helpers ----------------
__device__ __forceinline__ float getf(const void* p, size_t i, int isf32){
  return isf32 ? ((const float*)p)[i]
               : __bfloat162float(((const __hip_bfloat16*)p)[i]);
}
__device__ __forceinline__ int getedge(const void* p, long long idx, int is64, int n){
  long long v = is64 ? ((const long long*)p)[idx] : (long long)((const int*)p)[idx];
  v = v < 0 ? 0 : (v >= n ? (long long)(n - 1) : v);
  return (int)v;
}

__device__ __forceinline__ float bfly_sum(float v){
#pragma unroll
  for (int m = 32; m > 0; m >>= 1) v += __shfl_xor(v, m, 64);
  return v;
}

__device__ __forceinline__ float bf_lo(unsigned u){ return __uint_as_float(u << 16); }
__device__ __forceinline__ float bf_hi(unsigned u){ return __uint_as_float(u & 0xffff0000u); }

// ---------------- runtime dtype detection ----------------
__global__ __launch_bounds__(256) void detect_kernel(const void* x, const void* ei,
                                                     int* flags){
  __shared__ int cnt_sane, cnt_odd;
  int t = threadIdx.x;
  if (t == 0){ cnt_sane = 0; cnt_odd = 0; }
  __syncthreads();
  int sane = 0;
  for (int i = t; i < 4096; i += 256){
    float v = __bfloat162float(((const __hip_bfloat16*)x)[i]);
    if (fabsf(v) < 16.f) sane++;
  }
  atomicAdd(&cnt_sane, sane);
  int odd = 0;
  for (int i = t; i < 512; i += 256){
    if (((const int*)ei)[2 * i + 1] != 0) odd++;
  }
  atomicAdd(&cnt_odd, odd);
  __syncthreads();
  if (t == 0){
    flags[0] = (cnt_sane < 3900) ? 1 : 0;  // 1 => float inputs are fp32
    flags[1] = (cnt_odd == 0) ? 1 : 0;     // 1 => edge_index is int64
  }
}

// ---------------- graph bucketing ----------------
__global__ __launch_bounds__(256) void count_kernel(const void* __restrict__ ei, long long E,
                                                    int n, const int* __restrict__ flags,
                                                    int* __restrict__ cnt){
  int i = blockIdx.x * blockDim.x + threadIdx.x;
  if (i < E){
    int d = getedge(ei, E + i, flags[1], n);
    atomicAdd(&cnt[d], 1);
  }
}

// 4x-vectorized single-block scan
__global__ __launch_bounds__(1024) void scan_kernel(const int* __restrict__ cnt, int* __restrict__ off,
                                                    int* __restrict__ pos, int n){
  __shared__ int wsum[16];
  __shared__ int carry_s;
  int tid = threadIdx.x, lane = tid & 63, wv = tid >> 6;
  if (tid == 0) carry_s = 0;
  __syncthreads();
  for (int base = 0; base < n; base += 4096){
    int i0 = base + tid * 4;
    int v0 = 0, v1 = 0, v2 = 0, v3 = 0;
    if (i0 + 3 < n){
      int4 q = *(const int4*)(cnt + i0);
      v0 = q.x; v1 = q.y; v2 = q.z; v3 = q.w;
    } else {
      if (i0 < n)     v0 = cnt[i0];
      if (i0 + 1 < n) v1 = cnt[i0 + 1];
      if (i0 + 2 < n) v2 = cnt[i0 + 2];
      if (i0 + 3 < n) v3 = cnt[i0 + 3];
    }
    int s4 = v0 + v1 + v2 + v3;
    int s = s4;
#pragma unroll
    for (int o = 1; o < 64; o <<= 1){ int t = __shfl_up(s, o, 64); if (lane >= o) s += t; }
    if (lane == 63) wsum[wv] = s;
    __syncthreads();
    int wo = 0;
    for (int w = 0; w < wv; w++) wo += wsum[w];
    int carry = carry_s;
    int e0 = carry + wo + s - s4;
    if (i0 + 3 < n){
      int4 o4; o4.x = e0; o4.y = e0 + v0; o4.z = e0 + v0 + v1; o4.w = e0 + v0 + v1 + v2;
      *(int4*)(off + i0) = o4;
      *(int4*)(pos + i0) = o4;
    } else {
      if (i0 < n)     { off[i0] = e0;               pos[i0] = e0; }
      if (i0 + 1 < n) { off[i0+1] = e0+v0;          pos[i0+1] = e0+v0; }
      if (i0 + 2 < n) { off[i0+2] = e0+v0+v1;       pos[i0+2] = e0+v0+v1; }
      if (i0 + 3 < n) { off[i0+3] = e0+v0+v1+v2;    pos[i0+3] = e0+v0+v1+v2; }
    }
    __syncthreads();
    if (tid == 0){
      int tot = 0;
      for (int w = 0; w < 16; w++) tot += wsum[w];
      carry_s = carry + tot;
    }
    __syncthreads();
  }
  if (tid == 0) off[n] = carry_s;
}

__global__ __launch_bounds__(256) void fill_kernel(const void* __restrict__ ei, long long E,
                                                   int n, const int* __restrict__ flags,
                                                   int* __restrict__ pos, int* __restrict__ bsrc){
  int i = blockIdx.x * blockDim.x + threadIdx.x;
  if (i < E){
    int d = getedge(ei, E + i, flags[1], n);
    int s = getedge(ei, i, flags[1], n);
    int p = atomicAdd(&pos[d], 1);
    bsrc[p] = s;
  }
}

// ---------------- fused weight pre-transpose: Bt[N][K] (bf16) = W[K][N] ----------------
__global__ __launch_bounds__(256) void transpose_all_kernel(
    const void* __restrict__ Wp, const void* __restrict__ W0,
    const void* __restrict__ W1, const void* __restrict__ Wo,
    const int* __restrict__ flags,
    __hip_bfloat16* __restrict__ btp, __hip_bfloat16* __restrict__ bt0,
    __hip_bfloat16* __restrict__ bt1, __hip_bfloat16* __restrict__ bto)
{
  int f0 = flags[0];
  int o = blockIdx.x * 256 + threadIdx.x;
  const void* W; __hip_bfloat16* B; int K, N, loc;
  if (o < 65536)       { W = Wp; B = btp; K = 256; N = 256; loc = o; }
  else if (o < 131072) { W = W0; B = bt0; K = 256; N = 256; loc = o - 65536; }
  else if (o < 163840) { W = W1; B = bt1; K = 256; N = 128; loc = o - 131072; }
  else if (o < 180224) { W = Wo; B = bto; K = 128; N = 128; loc = o - 163840; }
  else return;
  int nn = loc / K, kk = loc - nn * K;
  B[loc] = __float2bfloat16(getf(W, (size_t)kk * N + nn, f0));
}

// ---------------- LDS-free direct-fragment MFMA GEMM ----------------
__device__ __forceinline__ bf16x8 pk8(f32x4 u, f32x4 w){
  bf16x8 r;
  r[0] = (__bf16)u.x; r[1] = (__bf16)u.y; r[2] = (__bf16)u.z; r[3] = (__bf16)u.w;
  r[4] = (__bf16)w.x; r[5] = (__bf16)w.y; r[6] = (__bf16)w.z; r[7] = (__bf16)w.w;
  return r;
}

template<int AMODE, bool OUTF, bool OUTB, bool RELU, bool BIAS, bool NORM, int ALMODE>
__global__ __launch_bounds__(256) void gemm_direct_kernel(
    const void* __restrict__ A, const __hip_bfloat16* __restrict__ Bt,
    const void* __restrict__ bias, const void* __restrict__ a_s, const void* __restrict__ a_d,
    const int* __restrict__ flags,
    float* __restrict__ Cf, __hip_bfloat16* __restrict__ Cb,
    float* __restrict__ als, float* __restrict__ ald,
    int M, int N, int K)
{
  const int f0 = flags[0];
  const bool af32 = (AMODE == 1) && (f0 != 0);
  int t = threadIdx.x;
  int wave = t >> 6, lane = t & 63;
  int q = lane >> 4, mi = lane & 15;
  int bm = blockIdx.x * 128 + wave * 32;
  int bn = blockIdx.y * 128;

  int r0 = min(bm + mi, M - 1);
  int r1 = min(bm + 16 + mi, M - 1);

  f32x4 acc[2][8] = {};

  if (af32){
    const float* Af = (const float*)A;
    const float* p0 = Af + (size_t)r0 * K + q * 8;
    const float* p1 = Af + (size_t)r1 * K + q * 8;
#pragma unroll 2
    for (int k0 = 0; k0 < K; k0 += 32){
      f32x4 u0 = *(const f32x4*)(p0 + k0);
      f32x4 w0 = *(const f32x4*)(p0 + k0 + 4);
      f32x4 u1 = *(const f32x4*)(p1 + k0);
      f32x4 w1 = *(const f32x4*)(p1 + k0 + 4);
      bf16x8 a0 = pk8(u0, w0);
      bf16x8 a1 = pk8(u1, w1);
#pragma unroll
      for (int nt = 0; nt < 8; nt++){
        bf16x8 b = *(const bf16x8*)(Bt + (size_t)(bn + nt * 16 + mi) * K + k0 + q * 8);
        acc[0][nt] = __builtin_amdgcn_mfma_f32_16x16x32_bf16(a0, b, acc[0][nt], 0, 0, 0);
        acc[1][nt] = __builtin_amdgcn_mfma_f32_16x16x32_bf16(a1, b, acc[1][nt], 0, 0, 0);
      }
    }
  } else {
    const __hip_bfloat16* Ab = (const __hip_bfloat16*)A;
    const __hip_bfloat16* p0 = Ab + (size_t)r0 * K + q * 8;
    const __hip_bfloat16* p1 = Ab + (size_t)r1 * K + q * 8;
#pragma unroll 2
    for (int k0 = 0; k0 < K; k0 += 32){
      bf16x8 a0 = *(const bf16x8*)(p0 + k0);
      bf16x8 a1 = *(const bf16x8*)(p1 + k0);
#pragma unroll
      for (int nt = 0; nt < 8; nt++){
        bf16x8 b = *(const bf16x8*)(Bt + (size_t)(bn + nt * 16 + mi) * K + k0 + q * 8);
        acc[0][nt] = __builtin_amdgcn_mfma_f32_16x16x32_bf16(a0, b, acc[0][nt], 0, 0, 0);
        acc[1][nt] = __builtin_amdgcn_mfma_f32_16x16x32_bf16(a1, b, acc[1][nt], 0, 0, 0);
      }
    }
  }

  float bv[8], asv[8], adv[8];
  if (BIAS){
#pragma unroll
    for (int nt = 0; nt < 8; nt++) bv[nt] = getf(bias, bn + nt * 16 + mi, f0);
  }
  if (ALMODE != 0){
#pragma unroll
    for (int nt = 0; nt < 8; nt++){
      asv[nt] = getf(a_s, bn + nt * 16 + mi, f0);
      adv[nt] = getf(a_d, bn + nt * 16 + mi, f0);
    }
  }
#pragma unroll
  for (int mt = 0; mt < 2; mt++){
#pragma unroll
    for (int r = 0; r < 4; r++){
      int row = bm + mt * 16 + q * 4 + r;
      float vv[8];
#pragma unroll
      for (int nt = 0; nt < 8; nt++){
        float v = acc[mt][nt][r];
        if (BIAS) v += bv[nt];
        if (RELU) v = fmaxf(v, 0.f);
        vv[nt] = v;
      }
      if (NORM){
        float ss = 0.f;
#pragma unroll
        for (int nt = 0; nt < 8; nt++) ss += vv[nt] * vv[nt];
        ss += __shfl_xor(ss, 1, 64);
        ss += __shfl_xor(ss, 2, 64);
        ss += __shfl_xor(ss, 4, 64);
        ss += __shfl_xor(ss, 8, 64);
        float inv = 1.f / fmaxf(sqrtf(ss), 1e-12f);
#pragma unroll
        for (int nt = 0; nt < 8; nt++) vv[nt] *= inv;
      }
      if (ALMODE == 1){
        float ps0 = 0.f, pd0 = 0.f, ps1 = 0.f, pd1 = 0.f;
#pragma unroll
        for (int nt = 0; nt < 4; nt++){ ps0 += vv[nt] * asv[nt]; pd0 += vv[nt] * adv[nt]; }
#pragma unroll
        for (int nt = 4; nt < 8; nt++){ ps1 += vv[nt] * asv[nt]; pd1 += vv[nt] * adv[nt]; }
#pragma unroll
        for (int m = 1; m < 16; m <<= 1){
          ps0 += __shfl_xor(ps0, m, 64); pd0 += __shfl_xor(pd0, m, 64);
          ps1 += __shfl_xor(ps1, m, 64); pd1 += __shfl_xor(pd1, m, 64);
        }
        if ((lane & 15) == 0 && row < M){
          int h0 = blockIdx.y * 2;
          als[(size_t)row * 4 + h0]     = ps0; ald[(size_t)row * 4 + h0]     = pd0;
          als[(size_t)row * 4 + h0 + 1] = ps1; ald[(size_t)row * 4 + h0 + 1] = pd1;
        }
      } else if (ALMODE == 2){
        float ps = 0.f, pd = 0.f;
#pragma unroll
        for (int nt = 0; nt < 8; nt++){ ps += vv[nt] * asv[nt]; pd += vv[nt] * adv[nt]; }
#pragma unroll
        for (int m = 1; m < 16; m <<= 1){
          ps += __shfl_xor(ps, m, 64); pd += __shfl_xor(pd, m, 64);
        }
        if ((lane & 15) == 0 && row < M){ als[row] = ps; ald[row] = pd; }
      }
      if (row < M){
#pragma unroll
        for (int nt = 0; nt < 8; nt++){
          int col = bn + nt * 16 + mi;
          size_t idx = (size_t)row * N + col;
          if (OUTF) Cf[idx] = vv[nt];
          if (OUTB) Cb[idx] = __float2bfloat16(vv[nt]);
        }
      }
    }
  }
}

#define FMA4(U, W) do { \
  m0 += (W) * bf_lo((U).x); m1 += (W) * bf_hi((U).x); \
  m2 += (W) * bf_lo((U).y); m3 += (W) * bf_hi((U).y); \
} while (0)

#define FMA2(U, W) do { \
  m0 += (W) * bf_lo(U); m1 += (W) * bf_hi(U); \
} while (0)

// ---------------- gather0: WAVE-per-node (proven structure), 8-deep pipeline ----------------
// lane owns 4 channels (ch = lane*4); head = lane>>4. Edge weights fused in-register.
// Denominator accumulates per-lane (identical within head group) -> no reductions.
__global__ __launch_bounds__(256) void gather0_kernel(
    const __hip_bfloat16* __restrict__ xw, const float* __restrict__ als, const float* __restrict__ ald,
    const int* __restrict__ bsrc, const int* __restrict__ off,
    const void* __restrict__ bias, const void* __restrict__ gamma,
    const void* __restrict__ beta, const int* __restrict__ flags,
    __hip_bfloat16* __restrict__ hbuf, int n)
{
  int f0 = flags[0];
  int t = threadIdx.x, wv = t >> 6, lane = t & 63;
  int i = blockIdx.x * 4 + wv;
  if (i >= n) return;
  int head = lane >> 4;
  int ch = lane * 4;
  int e0 = off[i], jend = off[i + 1];

  float m0 = 0.f, m1 = 0.f, m2 = 0.f, m3 = 0.f;
  float aldi = ald[(size_t)i * 4 + head];

  // self loop
  float se = als[(size_t)i * 4 + head] + aldi;
  se = (se > 0.f) ? se : 0.2f * se;
  float eself = __expf(se);
  {
    uint2 u = *(const uint2*)(xw + (size_t)i * 256 + ch);
    FMA4(u, eself);
  }
  float wacc = eself;

  int j = e0;
  // 8-deep main loop: 8 independent row loads in flight
  for (; j + 7 < jend; j += 8){
    int s0 = bsrc[j],     s1 = bsrc[j + 1], s2 = bsrc[j + 2], s3 = bsrc[j + 3];
    int s4 = bsrc[j + 4], s5 = bsrc[j + 5], s6 = bsrc[j + 6], s7 = bsrc[j + 7];
    float l0 = als[(size_t)s0 * 4 + head] + aldi;
    float l1 = als[(size_t)s1 * 4 + head] + aldi;
    float l2 = als[(size_t)s2 * 4 + head] + aldi;
    float l3 = als[(size_t)s3 * 4 + head] + aldi;
    float l4 = als[(size_t)s4 * 4 + head] + aldi;
    float l5 = als[(size_t)s5 * 4 + head] + aldi;
    float l6 = als[(size_t)s6 * 4 + head] + aldi;
    float l7 = als[(size_t)s7 * 4 + head] + aldi;
    l0 = (l0 > 0.f) ? l0 : 0.2f * l0;  l1 = (l1 > 0.f) ? l1 : 0.2f * l1;
    l2 = (l2 > 0.f) ? l2 : 0.2f * l2;  l3 = (l3 > 0.f) ? l3 : 0.2f * l3;
    l4 = (l4 > 0.f) ? l4 : 0.2f * l4;  l5 = (l5 > 0.f) ? l5 : 0.2f * l5;
    l6 = (l6 > 0.f) ? l6 : 0.2f * l6;  l7 = (l7 > 0.f) ? l7 : 0.2f * l7;
    float w0 = __expf(l0), w1 = __expf(l1), w2 = __expf(l2), w3 = __expf(l3);
    float w4 = __expf(l4), w5 = __expf(l5), w6 = __expf(l6), w7 = __expf(l7);
    uint2 U0 = *(const uint2*)(xw + (size_t)s0 * 256 + ch);
    uint2 U1 = *(const uint2*)(xw + (size_t)s1 * 256 + ch);
    uint2 U2 = *(const uint2*)(xw + (size_t)s2 * 256 + ch);
    uint2 U3 = *(const uint2*)(xw + (size_t)s3 * 256 + ch);
    uint2 U4 = *(const uint2*)(xw + (size_t)s4 * 256 + ch);
    uint2 U5 = *(const uint2*)(xw + (size_t)s5 * 256 + ch);
    uint2 U6 = *(const uint2*)(xw + (size_t)s6 * 256 + ch);
    uint2 U7 = *(const uint2*)(xw + (size_t)s7 * 256 + ch);
    wacc += w0 + w1 + w2 + w3 + w4 + w5 + w6 + w7;
    FMA4(U0, w0); FMA4(U1, w1); FMA4(U2, w2); FMA4(U3, w3);
    FMA4(U4, w4); FMA4(U5, w5); FMA4(U6, w6); FMA4(U7, w7);
  }
  for (; j + 3 < jend; j += 4){
    int s0 = bsrc[j], s1 = bsrc[j + 1], s2 = bsrc[j + 2], s3 = bsrc[j + 3];
    float l0 = als[(size_t)s0 * 4 + head] + aldi;
    float l1 = als[(size_t)s1 * 4 + head] + aldi;
    float l2 = als[(size_t)s2 * 4 + head] + aldi;
    float l3 = als[(size_t)s3 * 4 + head] + aldi;
    l0 = (l0 > 0.f) ? l0 : 0.2f * l0;  l1 = (l1 > 0.f) ? l1 : 0.2f * l1;
    l2 = (l2 > 0.f) ? l2 : 0.2f * l2;  l3 = (l3 > 0.f) ? l3 : 0.2f * l3;
    float w0 = __expf(l0), w1 = __expf(l1), w2 = __expf(l2), w3 = __expf(l3);
    uint2 U0 = *(const uint2*)(xw + (size_t)s0 * 256 + ch);
    uint2 U1 = *(const uint2*)(xw + (size_t)s1 * 256 + ch);
    uint2 U2 = *(const uint2*)(xw + (size_t)s2 * 256 + ch);
    uint2 U3 = *(const uint2*)(xw + (size_t)s3 * 256 + ch);
    wacc += w0 + w1 + w2 + w3;
    FMA4(U0, w0); FMA4(U1, w1); FMA4(U2, w2); FMA4(U3, w3);
  }
  for (; j < jend; j++){
    int s0 = bsrc[j];
    float l0 = als[(size_t)s0 * 4 + head] + aldi;
    l0 = (l0 > 0.f) ? l0 : 0.2f * l0;
    float w0 = __expf(l0);
    uint2 U0 = *(const uint2*)(xw + (size_t)s0 * 256 + ch);
    wacc += w0;
    FMA4(U0, w0);
  }

  // softmax denominator + bias
  float rl = 1.f / wacc;
  float v0 = m0 * rl + getf(bias, ch + 0, f0);
  float v1 = m1 * rl + getf(bias, ch + 1, f0);
  float v2 = m2 * rl + getf(bias, ch + 2, f0);
  float v3 = m3 * rl + getf(bias, ch + 3, f0);

  // in-wave LayerNorm over 256 channels
  float mu = bfly_sum(v0 + v1 + v2 + v3) * (1.f / 256.f);
  float d0 = v0 - mu, d1 = v1 - mu, d2 = v2 - mu, d3 = v3 - mu;
  float var = bfly_sum(d0 * d0 + d1 * d1 + d2 * d2 + d3 * d3) * (1.f / 256.f);
  float rs = rsqrtf(var + 1e-5f);

  bf16x4 rb = *(const bf16x4*)(hbuf + (size_t)i * 256 + ch);
  float y0 = fmaxf(d0 * rs * getf(gamma, ch + 0, f0) + getf(beta, ch + 0, f0) + (float)rb[0], 0.f);
  float y1 = fmaxf(d1 * rs * getf(gamma, ch + 1, f0) + getf(beta, ch + 1, f0) + (float)rb[1], 0.f);
  float y2 = fmaxf(d2 * rs * getf(gamma, ch + 2, f0) + getf(beta, ch + 2, f0) + (float)rb[2], 0.f);
  float y3 = fmaxf(d3 * rs * getf(gamma, ch + 3, f0) + getf(beta, ch + 3, f0) + (float)rb[3], 0.f);

  bf16x4 o;
  o[0] = (__bf16)y0; o[1] = (__bf16)y1; o[2] = (__bf16)y2; o[3] = (__bf16)y3;
  *(bf16x4*)(hbuf + (size_t)i * 256 + ch) = o;
}

// ---------------- gather1: WAVE-per-node, H=1, C=128, 8-deep pipeline ----------------
__global__ __launch_bounds__(256) void gather1_kernel(
    const __hip_bfloat16* __restrict__ xw, const float* __restrict__ als, const float* __restrict__ ald,
    const int* __restrict__ bsrc, const int* __restrict__ off,
    const void* __restrict__ bias, const void* __restrict__ gamma,
    const void* __restrict__ beta, const int* __restrict__ flags,
    __hip_bfloat16* __restrict__ outb, int n)
{
  int f0 = flags[0];
  int t = threadIdx.x, wv = t >> 6, lane = t & 63;
  int i = blockIdx.x * 4 + wv;
  if (i >= n) return;
  int ch = lane * 2;
  int e0 = off[i], jend = off[i + 1];

  float m0 = 0.f, m1 = 0.f;

  float aldi = ald[i];
  float se = als[i] + aldi;
  se = (se > 0.f) ? se : 0.2f * se;
  float eself = __expf(se);
  {
    unsigned u = *(const unsigned*)(xw + (size_t)i * 128 + ch);
    FMA2(u, eself);
  }
  float wacc = eself;

  int j = e0;
  for (; j + 7 < jend; j += 8){
    int s0 = bsrc[j],     s1 = bsrc[j + 1], s2 = bsrc[j + 2], s3 = bsrc[j + 3];
    int s4 = bsrc[j + 4], s5 = bsrc[j + 5], s6 = bsrc[j + 6], s7 = bsrc[j + 7];
    float l0 = als[s0] + aldi, l1 = als[s1] + aldi, l2 = als[s2] + aldi, l3 = als[s3] + aldi;
    float l4 = als[s4] + aldi, l5 = als[s5] + aldi, l6 = als[s6] + aldi, l7 = als[s7] + aldi;
    l0 = (l0 > 0.f) ? l0 : 0.2f * l0;  l1 = (l1 > 0.f) ? l1 : 0.2f * l1;
    l2 = (l2 > 0.f) ? l2 : 0.2f * l2;  l3 = (l3 > 0.f) ? l3 : 0.2f * l3;
    l4 = (l4 > 0.f) ? l4 : 0.2f * l4;  l5 = (l5 > 0.f) ? l5 : 0.2f * l5;
    l6 = (l6 > 0.f) ? l6 : 0.2f * l6;  l7 = (l7 > 0.f) ? l7 : 0.2f * l7;
    float w0 = __expf(l0), w1 = __expf(l1), w2 = __expf(l2), w3 = __expf(l3);
    float w4 = __expf(l4), w5 = __expf(l5), w6 = __expf(l6), w7 = __expf(l7);
    unsigned U0 = *(const unsigned*)(xw + (size_t)s0 * 128 + ch);
    unsigned U1 = *(const unsigned*)(xw + (size_t)s1 * 128 + ch);
    unsigned U2 = *(const unsigned*)(xw + (size_t)s2 * 128 + ch);
    unsigned U3 = *(const unsigned*)(xw + (size_t)s3 * 128 + ch);
    unsigned U4 = *(const unsigned*)(xw + (size_t)s4 * 128 + ch);
    unsigned U5 = *(const unsigned*)(xw + (size_t)s5 * 128 + ch);
    unsigned U6 = *(const unsigned*)(xw + (size_t)s6 * 128 + ch);
    unsigned U7 = *(const unsigned*)(xw + (size_t)s7 * 128 + ch);
    wacc += w0 + w1 + w2 + w3 + w4 + w5 + w6 + w7;
    FMA2(U0, w0); FMA2(U1, w1); FMA2(U2, w2); FMA2(U3, w3);
    FMA2(U4, w4); FMA2(U5, w5); FMA2(U6, w6); FMA2(U7, w7);
  }
  for (; j + 3 < jend; j += 4){
    int s0 = bsrc[j], s1 = bsrc[j + 1], s2 = bsrc[j + 2], s3 = bsrc[j + 3];
    float l0 = als[s0] + aldi, l1 = als[s1] + aldi, l2 = als[s2] + aldi, l3 = als[s3] + aldi;
    l0 = (l0 > 0.f) ? l0 : 0.2f * l0;  l1 = (l1 > 0.f) ? l1 : 0.2f * l1;
    l2 = (l2 > 0.f) ? l2 : 0.2f * l2;  l3 = (l3 > 0.f) ? l3 : 0.2f * l3;
    float w0 = __expf(l0), w1 = __expf(l1), w2 = __expf(l2), w3 = __expf(l3);
    unsigned U0 = *(const unsigned*)(xw + (size_t)s0 * 128 + ch);
    unsigned U1 = *(const unsigned*)(xw + (size_t)s1 * 128 + ch);
    unsigned U2 = *(const unsigned*)(xw + (size_t)s2 * 128 + ch);
    unsigned U3 = *(const unsigned*)(xw + (size_t)s3 * 128 + ch);
    wacc += w0 + w1 + w2 + w3;
    FMA2(U0, w0); FMA2(U1, w1); FMA2(U2, w2); FMA2(U3, w3);
  }
  for (; j < jend; j++){
    int s0 = bsrc[j];
    float l0 = als[s0] + aldi;
    l0 = (l0 > 0.f) ? l0 : 0.2f * l0;
    float w0 = __expf(l0);
    unsigned U0 = *(const unsigned*)(xw + (size_t)s0 * 128 + ch);
    wacc += w0;
    FMA2(U0, w0);
  }

  float rl = 1.f / wacc;
  float v0 = m0 * rl + getf(bias, ch + 0, f0);
  float v1 = m1 * rl + getf(bias, ch + 1, f0);

  float mu = bfly_sum(v0 + v1) * (1.f / 128.f);
  float d0 = v0 - mu, d1 = v1 - mu;
  float var = bfly_sum(d0 * d0 + d1 * d1) * (1.f / 128.f);
  float rs = rsqrtf(var + 1e-5f);

  float y0 = d0 * rs * getf(gamma, ch + 0, f0) + getf(beta, ch + 0, f0);
  float y1 = d1 * rs * getf(gamma, ch + 1, f0) + getf(beta, ch + 1, f0);

  bf16x2 o;
  o[0] = (__bf16)y0; o[1] = (__bf16)y1;
  *(bf16x2*)(outb + (size_t)i * 128 + ch) = o;
}

// ---------------- launch ----------------
extern "C" void kernel_launch(void* const* d_in, const int* in_sizes, int n_in,
                              void* d_out, int out_size, void* d_ws, size_t ws_size,
                              hipStream_t stream)
{
  const void* x   = d_in[0];
  const void* ei  = d_in[1];
  const void* Wp  = d_in[2];
  const void* bp  = d_in[3];
  const void* W0  = d_in[4];
  const void* as0 = d_in[5];
  const void* ad0 = d_in[6];
  const void* b0  = d_in[7];
  const void* W1  = d_in[8];
  const void* as1 = d_in[9];
  const void* ad1 = d_in[10];
  const void* b1  = d_in[11];
  const void* g0  = d_in[12];
  const void* be0 = d_in[13];
  const void* g1  = d_in[14];
  const void* be1 = d_in[15];
  const void* Wo  = d_in[16];
  const void* bo  = d_in[17];
  float* outp = (float*)d_out;

  const int n = in_sizes[0] / 256;   // 50000
  const int E = in_sizes[1] / 2;     // 800000

  char* w = (char*)d_ws;
  size_t SZ = (size_t)n * 256 * sizeof(float);
  __hip_bfloat16* h_bf  = (__hip_bfloat16*)w;             // h -> h1 -> h2 (bf16)
  __hip_bfloat16* xw_bf = (__hip_bfloat16*)(w + SZ / 2);  // xw0 -> xw1 (bf16)
  char* p = w + SZ;
  int* flags = (int*)p; p += 64;
  float* als0 = (float*)p; p += (size_t)n * 4 * sizeof(float);
  float* ald0 = (float*)p; p += (size_t)n * 4 * sizeof(float);
  float* als1 = (float*)p; p += (size_t)n * sizeof(float);
  float* ald1 = (float*)p; p += (size_t)n * sizeof(float);
  int* cnt    = (int*)p; p += (size_t)n * sizeof(int);
  int* offb   = (int*)p; p += (size_t)(n + 4) * sizeof(int);
  int* pos    = (int*)p; p += (size_t)n * sizeof(int);
  int* bsrc   = (int*)p; p += (size_t)E * sizeof(int);
  p = (char*)(((uintptr_t)p + 15) & ~(uintptr_t)15);
  __hip_bfloat16* bt_p = (__hip_bfloat16*)p; p += (size_t)256 * 256 * 2;
  __hip_bfloat16* bt_0 = (__hip_bfloat16*)p; p += (size_t)256 * 256 * 2;
  __hip_bfloat16* bt_1 = (__hip_bfloat16*)p; p += (size_t)128 * 256 * 2;
  __hip_bfloat16* bt_o = (__hip_bfloat16*)p; p += (size_t)128 * 128 * 2;

  detect_kernel<<<1, 256, 0, stream>>>(x, ei, flags);

  transpose_all_kernel<<<704, 256, 0, stream>>>(Wp, W0, W1, Wo, flags, bt_p, bt_0, bt_1, bt_o);

  (void)hipMemsetAsync(cnt, 0, (size_t)n * sizeof(int), stream);
  count_kernel<<<(E + 255) / 256, 256, 0, stream>>>(ei, E, n, flags, cnt);
  scan_kernel<<<1, 1024, 0, stream>>>(cnt, offb, pos, n);
  fill_kernel<<<(E + 255) / 256, 256, 0, stream>>>(ei, E, n, flags, pos, bsrc);

  int gm = (n + 127) / 128;
  int gn4 = (n + 3) / 4;

  // h = relu(x @ Wp + bp) -> bf16 only
  gemm_direct_kernel<1, false, true, true, true, false, 0><<<dim3(gm, 2), 256, 0, stream>>>(
      x, bt_p, bp, nullptr, nullptr, flags, nullptr, h_bf, nullptr, nullptr, n, 256, 256);
  // xw0 = h @ W0 (bf16) + fused als0/ald0
  gemm_direct_kernel<0, false, true, false, false, false, 1><<<dim3(gm, 2), 256, 0, stream>>>(
      h_bf, bt_0, nullptr, as0, ad0, flags, nullptr, xw_bf, als0, ald0, n, 256, 256);
  // layer-0 aggregate + b0 + LN + residual(bf16) + relu -> h1 in-place
  gather0_kernel<<<gn4, 256, 0, stream>>>(xw_bf, als0, ald0, bsrc, offb, b0, g0, be0,
                                          flags, h_bf, n);
  // xw1 = h1 @ W1 (bf16, n x 128) + fused als1/ald1
  gemm_direct_kernel<0, false, true, false, false, false, 2><<<dim3(gm, 1), 256, 0, stream>>>(
      h_bf, bt_1, nullptr, as1, ad1, flags, nullptr, xw_bf, als1, ald1, n, 128, 256);
  // layer-1 aggregate + b1 + LN -> h2 (bf16, into h_bf)
  gather1_kernel<<<gn4, 256, 0, stream>>>(xw_bf, als1, ald1, bsrc, offb, b1, g1, be1,
                                          flags, h_bf, n);
  // out = l2normalize(h2 @ Wo + bo), fused epilogue, direct to output
  gemm_direct_kernel<0, true, false, false, true, true, 0><<<dim3(gm, 1), 256, 0, stream>>>(
      h_bf, bt_o, bo, nullptr, nullptr, flags, outp, nullptr, nullptr, nullptr, n, 128, 128);
}

// Round 8
// 479.489 us; speedup vs baseline: 1.7137x; 1.0116x over previous
//
#include <hip/hip_runtime.h>
#include <hip/hip_bf16.h>

typedef __bf16 bf16x8 __attribute__((ext_vector_type(8)));
typedef __bf16 bf16x4 __attribute__((ext_vector_type(4)));
typedef __bf16 bf16x2 __attribute__((ext_vector_type(2)));
typedef float f32x4 __attribute__((ext_vector_type(4)));

// ---------------- dtype-robust load helpers ----------------
__device__ __forceinline__ float getf(const void* p, size_t i, int isf32){
  return isf32 ? ((const float*)p)[i]
               : __bfloat162float(((const __hip_bfloat16*)p)[i]);
}
__device__ __forceinline__ int getedge(const void* p, long long idx, int is64, int n){
  long long v = is64 ? ((const long long*)p)[idx] : (long long)((const int*)p)[idx];
  v = v < 0 ? 0 : (v >= n ? (long long)(n - 1) : v);
  return (int)v;
}

__device__ __forceinline__ float bfly_sum(float v){
#pragma unroll
  for (int m = 32; m > 0; m >>= 1) v += __shfl_xor(v, m, 64);
  return v;
}

__device__ __forceinline__ float bf_lo(unsigned u){ return __uint_as_float(u << 16); }
__device__ __forceinline__ float bf_hi(unsigned u){ return __uint_as_float(u & 0xffff0000u); }

// ---------------- runtime dtype detection ----------------
__global__ __launch_bounds__(256) void detect_kernel(const void* x, const void* ei,
                                                     int* flags){
  __shared__ int cnt_sane, cnt_odd;
  int t = threadIdx.x;
  if (t == 0){ cnt_sane = 0; cnt_odd = 0; }
  __syncthreads();
  int sane = 0;
  for (int i = t; i < 4096; i += 256){
    float v = __bfloat162float(((const __hip_bfloat16*)x)[i]);
    if (fabsf(v) < 16.f) sane++;
  }
  atomicAdd(&cnt_sane, sane);
  int odd = 0;
  for (int i = t; i < 512; i += 256){
    if (((const int*)ei)[2 * i + 1] != 0) odd++;
  }
  atomicAdd(&cnt_odd, odd);
  __syncthreads();
  if (t == 0){
    flags[0] = (cnt_sane < 3900) ? 1 : 0;  // 1 => float inputs are fp32
    flags[1] = (cnt_odd == 0) ? 1 : 0;     // 1 => edge_index is int64
  }
}

// ---------------- graph bucketing ----------------
__global__ __launch_bounds__(256) void count_kernel(const void* __restrict__ ei, long long E,
                                                    int n, const int* __restrict__ flags,
                                                    int* __restrict__ cnt){
  int i = blockIdx.x * blockDim.x + threadIdx.x;
  if (i < E){
    int d = getedge(ei, E + i, flags[1], n);
    atomicAdd(&cnt[d], 1);
  }
}

// ---------------- 3-phase parallel scan (4096 elems per 1024-thread block) ----------------
__global__ __launch_bounds__(1024) void scan_part_kernel(const int* __restrict__ cnt, int n,
                                                         int* __restrict__ bsum){
  __shared__ int wsum[16];
  int tid = threadIdx.x, lane = tid & 63, wv = tid >> 6;
  int i0 = blockIdx.x * 4096 + tid * 4;
  int s4 = 0;
  if (i0 + 3 < n){
    int4 q = *(const int4*)(cnt + i0);
    s4 = q.x + q.y + q.z + q.w;
  } else {
    if (i0 < n)     s4 += cnt[i0];
    if (i0 + 1 < n) s4 += cnt[i0 + 1];
    if (i0 + 2 < n) s4 += cnt[i0 + 2];
    if (i0 + 3 < n) s4 += cnt[i0 + 3];
  }
  int s = s4;
#pragma unroll
  for (int o = 1; o < 64; o <<= 1) s += __shfl_xor(s, o, 64);
  if (lane == 0) wsum[wv] = s;
  __syncthreads();
  if (tid == 0){
    int tot = 0;
    for (int w = 0; w < 16; w++) tot += wsum[w];
    bsum[blockIdx.x] = tot;
  }
}

__global__ __launch_bounds__(64) void scan_top_kernel(int* __restrict__ bsum, int nb,
                                                      int* __restrict__ off, int n){
  int lane = threadIdx.x;
  int v = (lane < nb) ? bsum[lane] : 0;
  int s = v;
#pragma unroll
  for (int o = 1; o < 64; o <<= 1){ int t = __shfl_up(s, o, 64); if (lane >= o) s += t; }
  if (lane < nb) bsum[lane] = s - v;   // exclusive block offsets
  if (lane == 63) off[n] = s;          // grand total
}

__global__ __launch_bounds__(1024) void scan_fin_kernel(const int* __restrict__ cnt, int n,
                                                        const int* __restrict__ bsum,
                                                        int* __restrict__ off, int* __restrict__ pos){
  __shared__ int wsum[16];
  int tid = threadIdx.x, lane = tid & 63, wv = tid >> 6;
  int i0 = blockIdx.x * 4096 + tid * 4;
  int v0 = 0, v1 = 0, v2 = 0, v3 = 0;
  if (i0 + 3 < n){
    int4 q = *(const int4*)(cnt + i0);
    v0 = q.x; v1 = q.y; v2 = q.z; v3 = q.w;
  } else {
    if (i0 < n)     v0 = cnt[i0];
    if (i0 + 1 < n) v1 = cnt[i0 + 1];
    if (i0 + 2 < n) v2 = cnt[i0 + 2];
    if (i0 + 3 < n) v3 = cnt[i0 + 3];
  }
  int s4 = v0 + v1 + v2 + v3;
  int s = s4;
#pragma unroll
  for (int o = 1; o < 64; o <<= 1){ int t = __shfl_up(s, o, 64); if (lane >= o) s += t; }
  if (lane == 63) wsum[wv] = s;
  __syncthreads();
  int wo = 0;
  for (int w = 0; w < wv; w++) wo += wsum[w];
  int e0 = bsum[blockIdx.x] + wo + s - s4;
  if (i0 + 3 < n){
    int4 o4; o4.x = e0; o4.y = e0 + v0; o4.z = e0 + v0 + v1; o4.w = e0 + v0 + v1 + v2;
    *(int4*)(off + i0) = o4;
    *(int4*)(pos + i0) = o4;
  } else {
    if (i0 < n)     { off[i0] = e0;               pos[i0] = e0; }
    if (i0 + 1 < n) { off[i0+1] = e0+v0;          pos[i0+1] = e0+v0; }
    if (i0 + 2 < n) { off[i0+2] = e0+v0+v1;       pos[i0+2] = e0+v0+v1; }
    if (i0 + 3 < n) { off[i0+3] = e0+v0+v1+v2;    pos[i0+3] = e0+v0+v1+v2; }
  }
}

__global__ __launch_bounds__(256) void fill_kernel(const void* __restrict__ ei, long long E,
                                                   int n, const int* __restrict__ flags,
                                                   int* __restrict__ pos, int* __restrict__ bsrc){
  int i = blockIdx.x * blockDim.x + threadIdx.x;
  if (i < E){
    int d = getedge(ei, E + i, flags[1], n);
    int s = getedge(ei, i, flags[1], n);
    int p = atomicAdd(&pos[d], 1);
    bsrc[p] = s;
  }
}

// ---------------- fused weight pre-transpose: Bt[N][K] (bf16) = W[K][N] ----------------
__global__ __launch_bounds__(256) void transpose_all_kernel(
    const void* __restrict__ Wp, const void* __restrict__ W0,
    const void* __restrict__ W1, const void* __restrict__ Wo,
    const int* __restrict__ flags,
    __hip_bfloat16* __restrict__ btp, __hip_bfloat16* __restrict__ bt0,
    __hip_bfloat16* __restrict__ bt1, __hip_bfloat16* __restrict__ bto)
{
  int f0 = flags[0];
  int o = blockIdx.x * 256 + threadIdx.x;
  const void* W; __hip_bfloat16* B; int K, N, loc;
  if (o < 65536)       { W = Wp; B = btp; K = 256; N = 256; loc = o; }
  else if (o < 131072) { W = W0; B = bt0; K = 256; N = 256; loc = o - 65536; }
  else if (o < 163840) { W = W1; B = bt1; K = 256; N = 128; loc = o - 131072; }
  else if (o < 180224) { W = Wo; B = bto; K = 128; N = 128; loc = o - 163840; }
  else return;
  int nn = loc / K, kk = loc - nn * K;
  B[loc] = __float2bfloat16(getf(W, (size_t)kk * N + nn, f0));
}

// ---------------- LDS-free direct-fragment MFMA GEMM ----------------
// Block = 128 rows x (NT*16) cols, 4 waves. NT=16 reads A exactly once (full width).
__device__ __forceinline__ bf16x8 pk8(f32x4 u, f32x4 w){
  bf16x8 r;
  r[0] = (__bf16)u.x; r[1] = (__bf16)u.y; r[2] = (__bf16)u.z; r[3] = (__bf16)u.w;
  r[4] = (__bf16)w.x; r[5] = (__bf16)w.y; r[6] = (__bf16)w.z; r[7] = (__bf16)w.w;
  return r;
}

template<int AMODE, bool OUTF, bool OUTB, bool RELU, bool BIAS, bool NORM, int ALMODE, int NT>
__global__ __launch_bounds__(256) void gemm_direct_kernel(
    const void* __restrict__ A, const __hip_bfloat16* __restrict__ Bt,
    const void* __restrict__ bias, const void* __restrict__ a_s, const void* __restrict__ a_d,
    const int* __restrict__ flags,
    float* __restrict__ Cf, __hip_bfloat16* __restrict__ Cb,
    float* __restrict__ als, float* __restrict__ ald,
    int M, int N, int K)
{
  const int f0 = flags[0];
  const bool af32 = (AMODE == 1) && (f0 != 0);
  int t = threadIdx.x;
  int wave = t >> 6, lane = t & 63;
  int q = lane >> 4, mi = lane & 15;
  int bm = blockIdx.x * 128 + wave * 32;
  int bn = blockIdx.y * (NT * 16);

  int r0 = min(bm + mi, M - 1);
  int r1 = min(bm + 16 + mi, M - 1);

  f32x4 acc[2][NT] = {};

  const float* pf0 = (const float*)A + (size_t)r0 * K + q * 8;
  const float* pf1 = (const float*)A + (size_t)r1 * K + q * 8;
  const __hip_bfloat16* pb0 = (const __hip_bfloat16*)A + (size_t)r0 * K + q * 8;
  const __hip_bfloat16* pb1 = (const __hip_bfloat16*)A + (size_t)r1 * K + q * 8;

  auto kstep = [&](int k0){
    bf16x8 a0, a1;
    if (af32){
      f32x4 u0 = *(const f32x4*)(pf0 + k0);
      f32x4 w0 = *(const f32x4*)(pf0 + k0 + 4);
      f32x4 u1 = *(const f32x4*)(pf1 + k0);
      f32x4 w1 = *(const f32x4*)(pf1 + k0 + 4);
      a0 = pk8(u0, w0);
      a1 = pk8(u1, w1);
    } else {
      a0 = *(const bf16x8*)(pb0 + k0);
      a1 = *(const bf16x8*)(pb1 + k0);
    }
#pragma unroll
    for (int nt = 0; nt < NT; nt++){
      bf16x8 b = *(const bf16x8*)(Bt + (size_t)(bn + nt * 16 + mi) * K + k0 + q * 8);
      acc[0][nt] = __builtin_amdgcn_mfma_f32_16x16x32_bf16(a0, b, acc[0][nt], 0, 0, 0);
      acc[1][nt] = __builtin_amdgcn_mfma_f32_16x16x32_bf16(a1, b, acc[1][nt], 0, 0, 0);
    }
  };
  if constexpr (NT == 8){
#pragma unroll 2
    for (int k0 = 0; k0 < K; k0 += 32) kstep(k0);
  } else {
#pragma unroll 1
    for (int k0 = 0; k0 < K; k0 += 32) kstep(k0);
  }

  float bv[NT], asv[NT], adv[NT];
  if (BIAS){
#pragma unroll
    for (int nt = 0; nt < NT; nt++) bv[nt] = getf(bias, bn + nt * 16 + mi, f0);
  }
  if (ALMODE != 0){
#pragma unroll
    for (int nt = 0; nt < NT; nt++){
      asv[nt] = getf(a_s, bn + nt * 16 + mi, f0);
      adv[nt] = getf(a_d, bn + nt * 16 + mi, f0);
    }
  }
#pragma unroll
  for (int mt = 0; mt < 2; mt++){
#pragma unroll
    for (int r = 0; r < 4; r++){
      int row = bm + mt * 16 + q * 4 + r;
      float vv[NT];
#pragma unroll
      for (int nt = 0; nt < NT; nt++){
        float v = acc[mt][nt][r];
        if (BIAS) v += bv[nt];
        if (RELU) v = fmaxf(v, 0.f);
        vv[nt] = v;
      }
      if (NORM){
        float ss = 0.f;
#pragma unroll
        for (int nt = 0; nt < NT; nt++) ss += vv[nt] * vv[nt];
        ss += __shfl_xor(ss, 1, 64);
        ss += __shfl_xor(ss, 2, 64);
        ss += __shfl_xor(ss, 4, 64);
        ss += __shfl_xor(ss, 8, 64);
        float inv = 1.f / fmaxf(sqrtf(ss), 1e-12f);
#pragma unroll
        for (int nt = 0; nt < NT; nt++) vv[nt] *= inv;
      }
      if (ALMODE == 1){
        // NT=16, N=256: 4 heads of 64 cols; head h covers nt in [4h, 4h+4)
        float ps[4] = {0.f, 0.f, 0.f, 0.f}, pd[4] = {0.f, 0.f, 0.f, 0.f};
#pragma unroll
        for (int h = 0; h < 4; h++){
#pragma unroll
          for (int g = 0; g < 4; g++){
            ps[h] += vv[h * 4 + g] * asv[h * 4 + g];
            pd[h] += vv[h * 4 + g] * adv[h * 4 + g];
          }
#pragma unroll
          for (int m = 1; m < 16; m <<= 1){
            ps[h] += __shfl_xor(ps[h], m, 64);
            pd[h] += __shfl_xor(pd[h], m, 64);
          }
        }
        if ((lane & 15) == 0 && row < M){
#pragma unroll
          for (int h = 0; h < 4; h++){
            als[(size_t)row * 4 + h] = ps[h];
            ald[(size_t)row * 4 + h] = pd[h];
          }
        }
      } else if (ALMODE == 2){
        float ps = 0.f, pd = 0.f;
#pragma unroll
        for (int nt = 0; nt < NT; nt++){ ps += vv[nt] * asv[nt]; pd += vv[nt] * adv[nt]; }
#pragma unroll
        for (int m = 1; m < 16; m <<= 1){
          ps += __shfl_xor(ps, m, 64); pd += __shfl_xor(pd, m, 64);
        }
        if ((lane & 15) == 0 && row < M){ als[row] = ps; ald[row] = pd; }
      }
      if (row < M){
#pragma unroll
        for (int nt = 0; nt < NT; nt++){
          int col = bn + nt * 16 + mi;
          size_t idx = (size_t)row * N + col;
          if (OUTF) Cf[idx] = vv[nt];
          if (OUTB) Cb[idx] = __float2bfloat16(vv[nt]);
        }
      }
    }
  }
}

#define FMA4(U, W) do { \
  m0 += (W) * bf_lo((U).x); m1 += (W) * bf_hi((U).x); \
  m2 += (W) * bf_lo((U).y); m3 += (W) * bf_hi((U).y); \
} while (0)

#define FMA2(U, W) do { \
  m0 += (W) * bf_lo(U); m1 += (W) * bf_hi(U); \
} while (0)

// ---------------- gather0: WAVE-per-node, 8-deep pipeline (proven) ----------------
__global__ __launch_bounds__(256) void gather0_kernel(
    const __hip_bfloat16* __restrict__ xw, const float* __restrict__ als, const float* __restrict__ ald,
    const int* __restrict__ bsrc, const int* __restrict__ off,
    const void* __restrict__ bias, const void* __restrict__ gamma,
    const void* __restrict__ beta, const int* __restrict__ flags,
    __hip_bfloat16* __restrict__ hbuf, int n)
{
  int f0 = flags[0];
  int t = threadIdx.x, wv = t >> 6, lane = t & 63;
  int i = blockIdx.x * 4 + wv;
  if (i >= n) return;
  int head = lane >> 4;
  int ch = lane * 4;
  int e0 = off[i], jend = off[i + 1];

  float m0 = 0.f, m1 = 0.f, m2 = 0.f, m3 = 0.f;
  float aldi = ald[(size_t)i * 4 + head];

  float se = als[(size_t)i * 4 + head] + aldi;
  se = (se > 0.f) ? se : 0.2f * se;
  float eself = __expf(se);
  {
    uint2 u = *(const uint2*)(xw + (size_t)i * 256 + ch);
    FMA4(u, eself);
  }
  float wacc = eself;

  int j = e0;
  for (; j + 7 < jend; j += 8){
    int s0 = bsrc[j],     s1 = bsrc[j + 1], s2 = bsrc[j + 2], s3 = bsrc[j + 3];
    int s4 = bsrc[j + 4], s5 = bsrc[j + 5], s6 = bsrc[j + 6], s7 = bsrc[j + 7];
    float l0 = als[(size_t)s0 * 4 + head] + aldi;
    float l1 = als[(size_t)s1 * 4 + head] + aldi;
    float l2 = als[(size_t)s2 * 4 + head] + aldi;
    float l3 = als[(size_t)s3 * 4 + head] + aldi;
    float l4 = als[(size_t)s4 * 4 + head] + aldi;
    float l5 = als[(size_t)s5 * 4 + head] + aldi;
    float l6 = als[(size_t)s6 * 4 + head] + aldi;
    float l7 = als[(size_t)s7 * 4 + head] + aldi;
    l0 = (l0 > 0.f) ? l0 : 0.2f * l0;  l1 = (l1 > 0.f) ? l1 : 0.2f * l1;
    l2 = (l2 > 0.f) ? l2 : 0.2f * l2;  l3 = (l3 > 0.f) ? l3 : 0.2f * l3;
    l4 = (l4 > 0.f) ? l4 : 0.2f * l4;  l5 = (l5 > 0.f) ? l5 : 0.2f * l5;
    l6 = (l6 > 0.f) ? l6 : 0.2f * l6;  l7 = (l7 > 0.f) ? l7 : 0.2f * l7;
    float w0 = __expf(l0), w1 = __expf(l1), w2 = __expf(l2), w3 = __expf(l3);
    float w4 = __expf(l4), w5 = __expf(l5), w6 = __expf(l6), w7 = __expf(l7);
    uint2 U0 = *(const uint2*)(xw + (size_t)s0 * 256 + ch);
    uint2 U1 = *(const uint2*)(xw + (size_t)s1 * 256 + ch);
    uint2 U2 = *(const uint2*)(xw + (size_t)s2 * 256 + ch);
    uint2 U3 = *(const uint2*)(xw + (size_t)s3 * 256 + ch);
    uint2 U4 = *(const uint2*)(xw + (size_t)s4 * 256 + ch);
    uint2 U5 = *(const uint2*)(xw + (size_t)s5 * 256 + ch);
    uint2 U6 = *(const uint2*)(xw + (size_t)s6 * 256 + ch);
    uint2 U7 = *(const uint2*)(xw + (size_t)s7 * 256 + ch);
    wacc += w0 + w1 + w2 + w3 + w4 + w5 + w6 + w7;
    FMA4(U0, w0); FMA4(U1, w1); FMA4(U2, w2); FMA4(U3, w3);
    FMA4(U4, w4); FMA4(U5, w5); FMA4(U6, w6); FMA4(U7, w7);
  }
  for (; j + 3 < jend; j += 4){
    int s0 = bsrc[j], s1 = bsrc[j + 1], s2 = bsrc[j + 2], s3 = bsrc[j + 3];
    float l0 = als[(size_t)s0 * 4 + head] + aldi;
    float l1 = als[(size_t)s1 * 4 + head] + aldi;
    float l2 = als[(size_t)s2 * 4 + head] + aldi;
    float l3 = als[(size_t)s3 * 4 + head] + aldi;
    l0 = (l0 > 0.f) ? l0 : 0.2f * l0;  l1 = (l1 > 0.f) ? l1 : 0.2f * l1;
    l2 = (l2 > 0.f) ? l2 : 0.2f * l2;  l3 = (l3 > 0.f) ? l3 : 0.2f * l3;
    float w0 = __expf(l0), w1 = __expf(l1), w2 = __expf(l2), w3 = __expf(l3);
    uint2 U0 = *(const uint2*)(xw + (size_t)s0 * 256 + ch);
    uint2 U1 = *(const uint2*)(xw + (size_t)s1 * 256 + ch);
    uint2 U2 = *(const uint2*)(xw + (size_t)s2 * 256 + ch);
    uint2 U3 = *(const uint2*)(xw + (size_t)s3 * 256 + ch);
    wacc += w0 + w1 + w2 + w3;
    FMA4(U0, w0); FMA4(U1, w1); FMA4(U2, w2); FMA4(U3, w3);
  }
  for (; j < jend; j++){
    int s0 = bsrc[j];
    float l0 = als[(size_t)s0 * 4 + head] + aldi;
    l0 = (l0 > 0.f) ? l0 : 0.2f * l0;
    float w0 = __expf(l0);
    uint2 U0 = *(const uint2*)(xw + (size_t)s0 * 256 + ch);
    wacc += w0;
    FMA4(U0, w0);
  }

  float rl = 1.f / wacc;
  float v0 = m0 * rl + getf(bias, ch + 0, f0);
  float v1 = m1 * rl + getf(bias, ch + 1, f0);
  float v2 = m2 * rl + getf(bias, ch + 2, f0);
  float v3 = m3 * rl + getf(bias, ch + 3, f0);

  float mu = bfly_sum(v0 + v1 + v2 + v3) * (1.f / 256.f);
  float d0 = v0 - mu, d1 = v1 - mu, d2 = v2 - mu, d3 = v3 - mu;
  float var = bfly_sum(d0 * d0 + d1 * d1 + d2 * d2 + d3 * d3) * (1.f / 256.f);
  float rs = rsqrtf(var + 1e-5f);

  bf16x4 rb = *(const bf16x4*)(hbuf + (size_t)i * 256 + ch);
  float y0 = fmaxf(d0 * rs * getf(gamma, ch + 0, f0) + getf(beta, ch + 0, f0) + (float)rb[0], 0.f);
  float y1 = fmaxf(d1 * rs * getf(gamma, ch + 1, f0) + getf(beta, ch + 1, f0) + (float)rb[1], 0.f);
  float y2 = fmaxf(d2 * rs * getf(gamma, ch + 2, f0) + getf(beta, ch + 2, f0) + (float)rb[2], 0.f);
  float y3 = fmaxf(d3 * rs * getf(gamma, ch + 3, f0) + getf(beta, ch + 3, f0) + (float)rb[3], 0.f);

  bf16x4 o;
  o[0] = (__bf16)y0; o[1] = (__bf16)y1; o[2] = (__bf16)y2; o[3] = (__bf16)y3;
  *(bf16x4*)(hbuf + (size_t)i * 256 + ch) = o;
}

// ---------------- gather1: WAVE-per-node, H=1, C=128, 8-deep pipeline ----------------
__global__ __launch_bounds__(256) void gather1_kernel(
    const __hip_bfloat16* __restrict__ xw, const float* __restrict__ als, const float* __restrict__ ald,
    const int* __restrict__ bsrc, const int* __restrict__ off,
    const void* __restrict__ bias, const void* __restrict__ gamma,
    const void* __restrict__ beta, const int* __restrict__ flags,
    __hip_bfloat16* __restrict__ outb, int n)
{
  int f0 = flags[0];
  int t = threadIdx.x, wv = t >> 6, lane = t & 63;
  int i = blockIdx.x * 4 + wv;
  if (i >= n) return;
  int ch = lane * 2;
  int e0 = off[i], jend = off[i + 1];

  float m0 = 0.f, m1 = 0.f;

  float aldi = ald[i];
  float se = als[i] + aldi;
  se = (se > 0.f) ? se : 0.2f * se;
  float eself = __expf(se);
  {
    unsigned u = *(const unsigned*)(xw + (size_t)i * 128 + ch);
    FMA2(u, eself);
  }
  float wacc = eself;

  int j = e0;
  for (; j + 7 < jend; j += 8){
    int s0 = bsrc[j],     s1 = bsrc[j + 1], s2 = bsrc[j + 2], s3 = bsrc[j + 3];
    int s4 = bsrc[j + 4], s5 = bsrc[j + 5], s6 = bsrc[j + 6], s7 = bsrc[j + 7];
    float l0 = als[s0] + aldi, l1 = als[s1] + aldi, l2 = als[s2] + aldi, l3 = als[s3] + aldi;
    float l4 = als[s4] + aldi, l5 = als[s5] + aldi, l6 = als[s6] + aldi, l7 = als[s7] + aldi;
    l0 = (l0 > 0.f) ? l0 : 0.2f * l0;  l1 = (l1 > 0.f) ? l1 : 0.2f * l1;
    l2 = (l2 > 0.f) ? l2 : 0.2f * l2;  l3 = (l3 > 0.f) ? l3 : 0.2f * l3;
    l4 = (l4 > 0.f) ? l4 : 0.2f * l4;  l5 = (l5 > 0.f) ? l5 : 0.2f * l5;
    l6 = (l6 > 0.f) ? l6 : 0.2f * l6;  l7 = (l7 > 0.f) ? l7 : 0.2f * l7;
    float w0 = __expf(l0), w1 = __expf(l1), w2 = __expf(l2), w3 = __expf(l3);
    float w4 = __expf(l4), w5 = __expf(l5), w6 = __expf(l6), w7 = __expf(l7);
    unsigned U0 = *(const unsigned*)(xw + (size_t)s0 * 128 + ch);
    unsigned U1 = *(const unsigned*)(xw + (size_t)s1 * 128 + ch);
    unsigned U2 = *(const unsigned*)(xw + (size_t)s2 * 128 + ch);
    unsigned U3 = *(const unsigned*)(xw + (size_t)s3 * 128 + ch);
    unsigned U4 = *(const unsigned*)(xw + (size_t)s4 * 128 + ch);
    unsigned U5 = *(const unsigned*)(xw + (size_t)s5 * 128 + ch);
    unsigned U6 = *(const unsigned*)(xw + (size_t)s6 * 128 + ch);
    unsigned U7 = *(const unsigned*)(xw + (size_t)s7 * 128 + ch);
    wacc += w0 + w1 + w2 + w3 + w4 + w5 + w6 + w7;
    FMA2(U0, w0); FMA2(U1, w1); FMA2(U2, w2); FMA2(U3, w3);
    FMA2(U4, w4); FMA2(U5, w5); FMA2(U6, w6); FMA2(U7, w7);
  }
  for (; j + 3 < jend; j += 4){
    int s0 = bsrc[j], s1 = bsrc[j + 1], s2 = bsrc[j + 2], s3 = bsrc[j + 3];
    float l0 = als[s0] + aldi, l1 = als[s1] + aldi, l2 = als[s2] + aldi, l3 = als[s3] + aldi;
    l0 = (l0 > 0.f) ? l0 : 0.2f * l0;  l1 = (l1 > 0.f) ? l1 : 0.2f * l1;
    l2 = (l2 > 0.f) ? l2 : 0.2f * l2;  l3 = (l3 > 0.f) ? l3 : 0.2f * l3;
    float w0 = __expf(l0), w1 = __expf(l1), w2 = __expf(l2), w3 = __expf(l3);
    unsigned U0 = *(const unsigned*)(xw + (size_t)s0 * 128 + ch);
    unsigned U1 = *(const unsigned*)(xw + (size_t)s1 * 128 + ch);
    unsigned U2 = *(const unsigned*)(xw + (size_t)s2 * 128 + ch);
    unsigned U3 = *(const unsigned*)(xw + (size_t)s3 * 128 + ch);
    wacc += w0 + w1 + w2 + w3;
    FMA2(U0, w0); FMA2(U1, w1); FMA2(U2, w2); FMA2(U3, w3);
  }
  for (; j < jend; j++){
    int s0 = bsrc[j];
    float l0 = als[s0] + aldi;
    l0 = (l0 > 0.f) ? l0 : 0.2f * l0;
    float w0 = __expf(l0);
    unsigned U0 = *(const unsigned*)(xw + (size_t)s0 * 128 + ch);
    wacc += w0;
    FMA2(U0, w0);
  }

  float rl = 1.f / wacc;
  float v0 = m0 * rl + getf(bias, ch + 0, f0);
  float v1 = m1 * rl + getf(bias, ch + 1, f0);

  float mu = bfly_sum(v0 + v1) * (1.f / 128.f);
  float d0 = v0 - mu, d1 = v1 - mu;
  float var = bfly_sum(d0 * d0 + d1 * d1) * (1.f / 128.f);
  float rs = rsqrtf(var + 1e-5f);

  float y0 = d0 * rs * getf(gamma, ch + 0, f0) + getf(beta, ch + 0, f0);
  float y1 = d1 * rs * getf(gamma, ch + 1, f0) + getf(beta, ch + 1, f0);

  bf16x2 o;
  o[0] = (__bf16)y0; o[1] = (__bf16)y1;
  *(bf16x2*)(outb + (size_t)i * 128 + ch) = o;
}

// ---------------- launch ----------------
extern "C" void kernel_launch(void* const* d_in, const int* in_sizes, int n_in,
                              void* d_out, int out_size, void* d_ws, size_t ws_size,
                              hipStream_t stream)
{
  const void* x   = d_in[0];
  const void* ei  = d_in[1];
  const void* Wp  = d_in[2];
  const void* bp  = d_in[3];
  const void* W0  = d_in[4];
  const void* as0 = d_in[5];
  const void* ad0 = d_in[6];
  const void* b0  = d_in[7];
  const void* W1  = d_in[8];
  const void* as1 = d_in[9];
  const void* ad1 = d_in[10];
  const void* b1  = d_in[11];
  const void* g0  = d_in[12];
  const void* be0 = d_in[13];
  const void* g1  = d_in[14];
  const void* be1 = d_in[15];
  const void* Wo  = d_in[16];
  const void* bo  = d_in[17];
  float* outp = (float*)d_out;

  const int n = in_sizes[0] / 256;   // 50000
  const int E = in_sizes[1] / 2;     // 800000

  char* w = (char*)d_ws;
  size_t SZ = (size_t)n * 256 * sizeof(float);
  __hip_bfloat16* h_bf  = (__hip_bfloat16*)w;             // h -> h1 -> h2 (bf16)
  __hip_bfloat16* xw_bf = (__hip_bfloat16*)(w + SZ / 2);  // xw0 -> xw1 (bf16)
  char* p = w + SZ;
  int* flags = (int*)p; p += 64;
  float* als0 = (float*)p; p += (size_t)n * 4 * sizeof(float);
  float* ald0 = (float*)p; p += (size_t)n * 4 * sizeof(float);
  float* als1 = (float*)p; p += (size_t)n * sizeof(float);
  float* ald1 = (float*)p; p += (size_t)n * sizeof(float);
  int* cnt    = (int*)p; p += (size_t)n * sizeof(int);
  int* offb   = (int*)p; p += (size_t)(n + 4) * sizeof(int);
  int* pos    = (int*)p; p += (size_t)n * sizeof(int);
  int* bsum   = (int*)p; p += 64 * sizeof(int);
  int* bsrc   = (int*)p; p += (size_t)E * sizeof(int);
  p = (char*)(((uintptr_t)p + 15) & ~(uintptr_t)15);
  __hip_bfloat16* bt_p = (__hip_bfloat16*)p; p += (size_t)256 * 256 * 2;
  __hip_bfloat16* bt_0 = (__hip_bfloat16*)p; p += (size_t)256 * 256 * 2;
  __hip_bfloat16* bt_1 = (__hip_bfloat16*)p; p += (size_t)128 * 256 * 2;
  __hip_bfloat16* bt_o = (__hip_bfloat16*)p; p += (size_t)128 * 128 * 2;

  detect_kernel<<<1, 256, 0, stream>>>(x, ei, flags);

  transpose_all_kernel<<<704, 256, 0, stream>>>(Wp, W0, W1, Wo, flags, bt_p, bt_0, bt_1, bt_o);

  (void)hipMemsetAsync(cnt, 0, (size_t)n * sizeof(int), stream);
  count_kernel<<<(E + 255) / 256, 256, 0, stream>>>(ei, E, n, flags, cnt);
  int nb = (n + 4095) / 4096;   // 13 for n=50000 (<=64 supported)
  scan_part_kernel<<<nb, 1024, 0, stream>>>(cnt, n, bsum);
  scan_top_kernel<<<1, 64, 0, stream>>>(bsum, nb, offb, n);
  scan_fin_kernel<<<nb, 1024, 0, stream>>>(cnt, n, bsum, offb, pos);
  fill_kernel<<<(E + 255) / 256, 256, 0, stream>>>(ei, E, n, flags, pos, bsrc);

  int gm = (n + 127) / 128;
  int gn4 = (n + 3) / 4;

  // h = relu(x @ Wp + bp) -> bf16, full-width tile (A read once)
  gemm_direct_kernel<1, false, true, true, true, false, 0, 16><<<dim3(gm, 1), 256, 0, stream>>>(
      x, bt_p, bp, nullptr, nullptr, flags, nullptr, h_bf, nullptr, nullptr, n, 256, 256);
  // xw0 = h @ W0 (bf16) + fused als0/ald0 (all 4 heads), full-width tile
  gemm_direct_kernel<0, false, true, false, false, false, 1, 16><<<dim3(gm, 1), 256, 0, stream>>>(
      h_bf, bt_0, nullptr, as0, ad0, flags, nullptr, xw_bf, als0, ald0, n, 256, 256);
  // layer-0 aggregate + b0 + LN + residual(bf16) + relu -> h1 in-place
  gather0_kernel<<<gn4, 256, 0, stream>>>(xw_bf, als0, ald0, bsrc, offb, b0, g0, be0,
                                          flags, h_bf, n);
  // xw1 = h1 @ W1 (bf16, n x 128) + fused als1/ald1
  gemm_direct_kernel<0, false, true, false, false, false, 2, 8><<<dim3(gm, 1), 256, 0, stream>>>(
      h_bf, bt_1, nullptr, as1, ad1, flags, nullptr, xw_bf, als1, ald1, n, 128, 256);
  // layer-1 aggregate + b1 + LN -> h2 (bf16, into h_bf)
  gather1_kernel<<<gn4, 256, 0, stream>>>(xw_bf, als1, ald1, bsrc, offb, b1, g1, be1,
                                          flags, h_bf, n);
  // out = l2normalize(h2 @ Wo + bo), fused epilogue, direct to output
  gemm_direct_kernel<0, true, false, false, true, true, 0, 8><<<dim3(gm, 1), 256, 0, stream>>>(
      h_bf, bt_o, bo, nullptr, nullptr, flags, outp, nullptr, nullptr, nullptr, n, 128, 128);
}